// Round 10
// baseline (1729.862 us; speedup 1.0000x reference)
//
#include <hip/hip_runtime.h>
#include <hip/hip_bf16.h>
#include <cstdint>
#include <cfloat>
#include <cstddef>
#include <type_traits>

#define N_NODES 24576
#define B_GRAPHS 128
#define D_IN 92
#define D_INP 96           // D_IN padded to multiple of 32 for MFMA K
#define DMODEL 512
#define NHEAD 8
#define HDIM 64
#define NLAYER 3
#define DFF 2048

typedef __attribute__((ext_vector_type(8))) short short8;
typedef __attribute__((ext_vector_type(4))) short short4v;
typedef __attribute__((ext_vector_type(8))) unsigned short ushort8;
typedef __attribute__((ext_vector_type(4))) float f32x4;

__device__ __forceinline__ float b2f(unsigned short u) {
  union { unsigned int i; float f; } x;
  x.i = ((unsigned int)u) << 16;
  return x.f;
}
__device__ __forceinline__ unsigned short f2b(float f) {
  __hip_bfloat16 h = __float2bfloat16(f);
  return *reinterpret_cast<unsigned short*>(&h);
}

// async global->LDS, 16B per lane; LDS dest = wave-uniform base + lane*16
__device__ __forceinline__ void gl2lds16(const __hip_bfloat16* g,
                                         __hip_bfloat16* l) {
  __builtin_amdgcn_global_load_lds(
      (const __attribute__((address_space(1))) unsigned int*)g,
      (__attribute__((address_space(3))) unsigned int*)l, 16, 0, 0);
}

// ---------------------------------------------------------------------------
// starts[g] = lower_bound(batch, g); handles int32 or int64 batch (sniffed).
__global__ void starts_k(const int* __restrict__ batch32, int* __restrict__ starts) {
  __shared__ int is64_s;
  const int tid = threadIdx.x;
  if (tid == 0) is64_s = 0;
  __syncthreads();
  int bad = 0;
  for (int i = tid; i < N_NODES - 1; i += 256)
    if (batch32[i] > batch32[i + 1]) bad = 1;
  if (bad) atomicOr(&is64_s, 1);
  __syncthreads();
  const int is64 = is64_s;
  if (tid <= B_GRAPHS) {
    int lo = 0, hi = N_NODES;
    while (lo < hi) {
      int mid = (lo + hi) >> 1;
      int v = is64 ? batch32[2 * mid] : batch32[mid];
      if (v < tid) lo = mid + 1; else hi = mid;
    }
    starts[tid] = lo;
  }
}

// ---------------------------------------------------------------------------
// fp32 -> bf16 flat convert (count multiple of 4)
__global__ __launch_bounds__(256) void cvt_k(const float* __restrict__ in,
                                             __hip_bfloat16* __restrict__ out,
                                             int count4) {
  int i = blockIdx.x * 256 + threadIdx.x;
  if (i < count4) {
    float4 v = ((const float4*)in)[i];
    short4v o;
    o[0] = (short)f2b(v.x); o[1] = (short)f2b(v.y);
    o[2] = (short)f2b(v.z); o[3] = (short)f2b(v.w);
    ((short4v*)out)[i] = o;
  }
}

// fp32 (rows x 92) -> bf16 (rows x 96), zero-padded tail
__global__ __launch_bounds__(256) void padcvt_k(const float* __restrict__ in,
                                                __hip_bfloat16* __restrict__ out,
                                                int rows) {
  int idx = blockIdx.x * 256 + threadIdx.x;
  if (idx < rows * D_INP) {
    int r = idx / D_INP, c = idx - r * D_INP;
    out[idx] = __float2bfloat16(c < D_IN ? in[(size_t)r * D_IN + c] : 0.0f);
  }
}

// ---------------------------------------------------------------------------
// bf16 MFMA GEMM: C[m][n] = act( A[m][:] . W[n][:] + bias[n] + res[m][n] )
// A: MxK bf16 row-major, W: NxK bf16 row-major. M%128==0, N%256==0, K%32==0.
// 128x256 tile, BK=32, 256 threads = 4 waves (wave = 64x128 quadrant,
// 4m x 8n sub-tiles = 32 MFMA per K-iter — AITER's ~32-MFMA-per-barrier
// design point). Triple-buffered staging with raw `s_waitcnt vmcnt(6);
// s_barrier`: each tile's loads get two compute phases of flight; barrier
// waits only the tile about to be consumed. Each wave issues 6 loads/tile.
// LDS chunk swizzle (verified r9: conflicts 4.7M -> 0): staging lane
// (r16 = lane>>2, p = lane&3) fetches global k-chunk (p + (r16>>1))&3;
// reader picks position (quad - (l16>>1))&3. Depends only on row mod 16.
// 1D grid, XCD-aware swizzle (i%8 -> XCD): per-XCD contiguous row stripes.
__global__ __launch_bounds__(256, 2) void mgemm_k(
    const __hip_bfloat16* __restrict__ A, const __hip_bfloat16* __restrict__ W,
    const float* __restrict__ bias, const __hip_bfloat16* __restrict__ res,
    __hip_bfloat16* __restrict__ C, int M, int N, int K, int act) {
  __shared__ __align__(16) __hip_bfloat16 As[3][128 * 32];
  __shared__ __align__(16) __hip_bfloat16 Ws[3][256 * 32];
  const int tid = threadIdx.x;
  const int wave = tid >> 6, lane = tid & 63;

  const int nxt = N >> 8, nmt = M >> 7;
  int rowt, colt;
  if ((nmt & 7) == 0) {
    const int rows_per = nmt >> 3;      // row tiles per XCD stripe
    const int x = blockIdx.x & 7;       // XCD (dispatch round-robin)
    const int j = blockIdx.x >> 3;
    rowt = x * rows_per + j % rows_per; // col-major within stripe
    colt = j / rows_per;
  } else {
    rowt = blockIdx.x / nxt;
    colt = blockIdx.x % nxt;
  }
  const int m0 = rowt * 128, n0 = colt * 256;

  const int mw = (wave >> 1) * 64, nw = (wave & 1) * 128;
  const int quad = lane >> 4, l16 = lane & 15;

  f32x4 acc[4][8] = {};

  // staging map: r16 = lane>>2 (row within 16-group), p = lane&3 (chunk slot)
  const int r16 = lane >> 2;
  const int swz = (((lane & 3) + (r16 >> 1)) & 3) * 8;
  const int arow = wave * 32 + r16;     // A: wave stages rows [w*32, w*32+32)
  const int wrow = wave * 64 + r16;     // W: wave stages rows [w*64, w*64+64)
  const __hip_bfloat16* gA = A + (size_t)(m0 + arow) * K + swz;
  const __hip_bfloat16* gW = W + (size_t)(n0 + wrow) * K + swz;
  const int loA = wave * 32 * 32;
  const int loW = wave * 64 * 32;

  const int niter = K >> 5;
#define STAGE(T, BUF)                                                     \
  do {                                                                    \
    const int k_ = (T) * 32;                                              \
    gl2lds16(gA + k_, &As[BUF][loA]);                                     \
    gl2lds16(gA + (size_t)16 * K + k_, &As[BUF][loA + 16 * 32]);          \
    gl2lds16(gW + k_, &Ws[BUF][loW]);                                     \
    gl2lds16(gW + (size_t)16 * K + k_, &Ws[BUF][loW + 16 * 32]);          \
    gl2lds16(gW + (size_t)32 * K + k_, &Ws[BUF][loW + 32 * 32]);          \
    gl2lds16(gW + (size_t)48 * K + k_, &Ws[BUF][loW + 48 * 32]);          \
  } while (0)

  STAGE(0, 0);
  if (niter > 1) STAGE(1, 1);

  // reader chunk position for this lane (row-mod-16 invariant)
  const int prd = ((quad - (l16 >> 1)) & 3) * 8;

  for (int it = 0; it < niter; ++it) {
    // wait for tile `it` only (6 of our loads); keep tile it+1 in flight.
    if (it + 1 < niter)
      asm volatile("s_waitcnt vmcnt(6)\n\ts_barrier" ::: "memory");
    else
      asm volatile("s_waitcnt vmcnt(0)\n\ts_barrier" ::: "memory");
    // prefetch tile it+2 into the buffer last read at iter it-1.
    if (it + 2 < niter) STAGE(it + 2, (it + 2) % 3);
    const int cb = it % 3;
    short8 af[4], bf[8];
#pragma unroll
    for (int t = 0; t < 4; t++)
      af[t] = *(const short8*)&As[cb][(mw + t * 16 + l16) * 32 + prd];
#pragma unroll
    for (int t = 0; t < 8; t++)
      bf[t] = *(const short8*)&Ws[cb][(nw + t * 16 + l16) * 32 + prd];
#pragma unroll
    for (int mt = 0; mt < 4; mt++)
#pragma unroll
      for (int nt = 0; nt < 8; nt++)
        acc[mt][nt] = __builtin_amdgcn_mfma_f32_16x16x32_bf16(
            af[mt], bf[nt], acc[mt][nt], 0, 0, 0);
  }
#undef STAGE

#pragma unroll
  for (int mt = 0; mt < 4; mt++) {
#pragma unroll
    for (int nt = 0; nt < 8; nt++) {
      const int n = n0 + nw + nt * 16 + l16;
      const float bv = bias[n];
#pragma unroll
      for (int i = 0; i < 4; i++) {
        const int m = m0 + mw + mt * 16 + quad * 4 + i;
        float v = acc[mt][nt][i] + bv;
        if (res) v += __bfloat162float(res[(size_t)m * N + n]);
        if (act == 1) v = fmaxf(v, 0.0f);
        C[(size_t)m * N + n] = __float2bfloat16(v);
      }
    }
  }
}

// ---------------------------------------------------------------------------
// fp32 SIMT GEMM (kept for the tiny head): 64x64 tile.
__global__ __launch_bounds__(256) void gemm_k(
    const float* __restrict__ A, const float* __restrict__ W,
    const float* __restrict__ bias, const float* __restrict__ res,
    float* __restrict__ C, int M, int N, int K, int act) {
  __shared__ float As[16][68];
  __shared__ float Ws[16][68];
  const int tid = threadIdx.x;
  const int tx = tid & 15, ty = tid >> 4;
  const int m0 = blockIdx.y * 64, n0 = blockIdx.x * 64;
  const int lr = tid >> 2;
  const int lk = (tid & 3) * 4;
  float acc[4][4] = {{0.f}};
  for (int k0 = 0; k0 < K; k0 += 16) {
#pragma unroll
    for (int i = 0; i < 4; i++) {
      int k = k0 + lk + i;
      As[lk + i][lr] = (k < K) ? A[(size_t)(m0 + lr) * K + k] : 0.0f;
      Ws[lk + i][lr] = (k < K) ? W[(size_t)(n0 + lr) * K + k] : 0.0f;
    }
    __syncthreads();
#pragma unroll
    for (int kk = 0; kk < 16; kk++) {
      float4 a4 = *(const float4*)&As[kk][ty * 4];
      float4 w4 = *(const float4*)&Ws[kk][tx * 4];
      float a[4] = {a4.x, a4.y, a4.z, a4.w};
      float w[4] = {w4.x, w4.y, w4.z, w4.w};
#pragma unroll
      for (int i = 0; i < 4; i++)
#pragma unroll
        for (int j = 0; j < 4; j++) acc[i][j] += a[i] * w[j];
    }
    __syncthreads();
  }
#pragma unroll
  for (int i = 0; i < 4; i++) {
    int m = m0 + ty * 4 + i;
#pragma unroll
    for (int j = 0; j < 4; j++) {
      int n = n0 + tx * 4 + j;
      float v = acc[i][j] + bias[n];
      if (res) v += res[(size_t)m * N + n];
      if (act == 1) v = fmaxf(v, 0.0f);
      else if (act == 2) v = v / (1.0f + __expf(-v));
      C[(size_t)m * N + n] = v;
    }
  }
}

// ---------------------------------------------------------------------------
// Row LayerNorm over D=512, bf16 in/out, fp32 params. 4 rows/block.
__global__ __launch_bounds__(256) void lnb_k(
    const __hip_bfloat16* __restrict__ in, const float* __restrict__ g,
    const float* __restrict__ b, __hip_bfloat16* __restrict__ out) {
  int row = blockIdx.x * 4 + (threadIdx.x >> 6);
  int lane = threadIdx.x & 63;
  const unsigned short* rp =
      (const unsigned short*)in + (size_t)row * DMODEL + lane * 8;
  ushort8 sv = *(const ushort8*)rp;
  float v[8];
  float s = 0.f;
#pragma unroll
  for (int i = 0; i < 8; i++) { v[i] = b2f(sv[i]); s += v[i]; }
#pragma unroll
  for (int off = 32; off; off >>= 1) s += __shfl_xor(s, off);
  float mu = s * (1.0f / DMODEL);
  float vs = 0.f;
#pragma unroll
  for (int i = 0; i < 8; i++) { float d = v[i] - mu; vs += d * d; }
#pragma unroll
  for (int off = 32; off; off >>= 1) vs += __shfl_xor(vs, off);
  float rs = rsqrtf(vs * (1.0f / DMODEL) + 1e-5f);
  ushort8 o;
#pragma unroll
  for (int i = 0; i < 8; i++) {
    int c = lane * 8 + i;
    o[i] = f2b((v[i] - mu) * rs * g[c] + b[c]);
  }
  *(ushort8*)((unsigned short*)out + (size_t)row * DMODEL + lane * 8) = o;
}

// ---------------------------------------------------------------------------
// MFMA ragged attention, key-split flash halves.
// Block = (graph, head, key-half); 4 waves. Each half computes, for EVERY
// query q of the graph: O'[q] = sum_{k in half} e^{s_qk - m_half} V_k (bf16,
// unnormalized) plus (m_half, l_half) into ml[]. merge_k renormalizes.
// LDS: Ks[128][72] + Vt[64][136] + Ps[4][16][136] = 52 KB -> 3 blocks/CU.
#define MAXNH 128
__global__ __launch_bounds__(256, 3) void attn5_k(
    const __hip_bfloat16* __restrict__ qkv, const int* __restrict__ starts,
    __hip_bfloat16* __restrict__ O1, __hip_bfloat16* __restrict__ O2,
    float* __restrict__ ml) {
  const int half = blockIdx.x & 1;
  const int gh = blockIdx.x >> 1;
  const int g = gh >> 3, h = gh & 7;
  int s0 = starts[g], s1 = starts[g + 1];
  s0 = min(max(s0, 0), N_NODES);
  s1 = min(max(s1, s0), N_NODES);
  const int n = s1 - s0, start = s0;
  if (n == 0) return;
  const int tid = threadIdx.x, wave = tid >> 6, lane = tid & 63;
  const int quad = lane >> 4, l16 = lane & 15;
  unsigned short* Oh = (unsigned short*)(half ? O2 : O1);

  __shared__ __align__(16) unsigned short Ks[128][72];     // K rows [key][d]
  __shared__ __align__(16) unsigned short Vt[64][136];     // V^T [d][key]
  __shared__ __align__(16) unsigned short Ps[4][16][136];  // per-wave P[q][key]

  if (n <= 2 * MAXNH) {
    const int nh1 = (n + 1) >> 1;
    const int k0g = half * nh1;                 // this half's first key
    const int nh = half ? (n - nh1) : nh1;      // this half's key count
    const int ktq = (n + 15) >> 4;              // query tiles (full n)

    if (nh == 0) {  // empty half (n==1): emit zero partials for all queries
      for (int mt = wave; mt < ktq; mt += 4) {
        const int q = mt * 16 + l16;
        if (q < n) {
          short4v z = {0, 0, 0, 0};
#pragma unroll
          for (int dt = 0; dt < 4; dt++)
            *(short4v*)(Oh + (size_t)(start + q) * DMODEL + h * HDIM +
                        dt * 16 + quad * 4) = z;
          if (quad == 0) {
            float2 mlv = {-FLT_MAX, 0.0f};
            *(float2*)(ml + ((size_t)(start + q) * NHEAD + h) * 4 + half * 2) = mlv;
          }
        }
      }
      return;
    }

    // ---- stage K rows of this half ----
    for (int idx = tid; idx < nh * 8; idx += 256) {
      int r = idx >> 3, c = (idx & 7) * 8;
      *(ushort8*)&Ks[r][c] = *(const ushort8*)((const unsigned short*)qkv +
                                               (size_t)(start + k0g + r) * 1536 +
                                               512 + h * HDIM + c);
    }
    // zero K pad rows [nh, min(128, nh+16))
    for (int idx = tid; idx < 16 * 8; idx += 256) {
      int r = nh + (idx >> 3), c = (idx & 7) * 8;
      if (r < 128) {
        ushort8 z = {0, 0, 0, 0, 0, 0, 0, 0};
        *(ushort8*)&Ks[r][c] = z;
      }
    }
    // ---- stage V transposed: Vt[d][r] = V[k0g+r][d] ----
    const int vr = tid & 31, dc8 = tid >> 5;
    for (int r0 = 0; r0 < nh; r0 += 32) {
      int r = r0 + vr;
      if (r < nh) {
        ushort8 v = *(const ushort8*)((const unsigned short*)qkv +
                                      (size_t)(start + k0g + r) * 1536 + 1024 +
                                      h * HDIM + dc8 * 8);
#pragma unroll
        for (int j = 0; j < 8; j++) Vt[dc8 * 8 + j][r] = v[j];
      }
    }
    // zero key cols [nh, nh+32)
    for (int idx = tid; idx < 64 * 32; idx += 256) {
      int d = idx >> 5, r = nh + (idx & 31);
      if (r < 136) Vt[d][r] = 0;
    }
    __syncthreads();

    const int ktmax2 = (nh + 15) >> 4;  // key tiles in this half (<=8)
    const int nkc2 = (nh + 31) >> 5;    // 32-wide key chunks (<=4)
    const float scale = 0.125f;

    for (int mt = wave; mt < ktq; mt += 4) {
      // Q fragments: lane l16 = q, dims quad*8..+7 per 32-chunk
      const int qrow = start + min(mt * 16 + l16, n - 1);
      const short8 qf0 = *(const short8*)((const unsigned short*)qkv +
                                          (size_t)qrow * 1536 + h * HDIM + quad * 8);
      const short8 qf1 = *(const short8*)((const unsigned short*)qkv +
                                          (size_t)qrow * 1536 + h * HDIM + 32 + quad * 8);
      f32x4 sacc[8];
      // ---- scores: S^T[key][q] = K . Q^T (K-frags from LDS) ----
#pragma unroll
      for (int kt = 0; kt < 8; kt++) {
        if (kt < ktmax2) {
          const int krow = kt * 16 + l16;
          const short8 kf0 = *(const short8*)&Ks[krow][quad * 8];
          const short8 kf1 = *(const short8*)&Ks[krow][32 + quad * 8];
          f32x4 a = {0.f, 0.f, 0.f, 0.f};
          a = __builtin_amdgcn_mfma_f32_16x16x32_bf16(kf0, qf0, a, 0, 0, 0);
          a = __builtin_amdgcn_mfma_f32_16x16x32_bf16(kf1, qf1, a, 0, 0, 0);
          sacc[kt] = a;
        }
      }
      // ---- local softmax stats for q = l16 over this half's keys ----
      float mx = -FLT_MAX;
#pragma unroll
      for (int kt = 0; kt < 8; kt++) {
        if (kt < ktmax2) {
#pragma unroll
          for (int i = 0; i < 4; i++) {
            const int key = kt * 16 + quad * 4 + i;
            const float v = sacc[kt][i] * scale;
            sacc[kt][i] = v;
            if (key < nh) mx = fmaxf(mx, v);
          }
        }
      }
      mx = fmaxf(mx, __shfl_xor(mx, 16));
      mx = fmaxf(mx, __shfl_xor(mx, 32));
      float ls = 0.f;
#pragma unroll
      for (int kt = 0; kt < 8; kt++) {
        if (kt < ktmax2) {
#pragma unroll
          for (int i = 0; i < 4; i++) {
            const int key = kt * 16 + quad * 4 + i;
            const float p = (key < nh) ? __expf(sacc[kt][i] - mx) : 0.0f;
            sacc[kt][i] = p;
            ls += p;
          }
        }
      }
      ls += __shfl_xor(ls, 16);
      ls += __shfl_xor(ls, 32);
      // ---- store UNNORMALIZED p (bf16) to Ps; zero kt in [ktmax2, 2*nkc2) ----
#pragma unroll
      for (int kt = 0; kt < 8; kt++) {
        if (kt < 2 * nkc2) {
          short4v pp;
#pragma unroll
          for (int i = 0; i < 4; i++) {
            const float p = (kt < ktmax2) ? sacc[kt][i] : 0.0f;
            pp[i] = (short)f2b(p);
          }
          *(short4v*)&Ps[wave][l16][kt * 16 + quad * 4] = pp;
        }
      }
      __threadfence_block();  // wave-local LDS write->read ordering
      // ---- PV: O'[d][q] = sum_key V^T[d][key] * p[q][key] ----
      const int qv = mt * 16 + l16;
#pragma unroll
      for (int dt = 0; dt < 4; dt++) {
        f32x4 oa = {0.f, 0.f, 0.f, 0.f};
#pragma unroll
        for (int kc = 0; kc < 4; kc++) {
          if (kc < nkc2) {
            const short8 vf = *(const short8*)&Vt[dt * 16 + l16][kc * 32 + quad * 8];
            const short8 pf = *(const short8*)&Ps[wave][l16][kc * 32 + quad * 8];
            oa = __builtin_amdgcn_mfma_f32_16x16x32_bf16(vf, pf, oa, 0, 0, 0);
          }
        }
        if (qv < n) {
          short4v ov;
#pragma unroll
          for (int i = 0; i < 4; i++) ov[i] = (short)f2b(oa[i]);
          *(short4v*)(Oh + (size_t)(start + qv) * DMODEL + h * HDIM +
                      dt * 16 + quad * 4) = ov;
        }
      }
      if (qv < n && quad == 0) {
        float2 mlv = {mx, ls};
        *(float2*)(ml + ((size_t)(start + qv) * NHEAD + h) * 4 + half * 2) = mlv;
      }
    }
  } else {
    // fallback (n in (256,512]; statistically never). half 0 computes the
    // full normalized attention -> O1, ml=(0,1); half 1 emits zero partials.
    const float scale = 0.125f;
    int nn = min(n, 512);
    if (half == 1) {
      for (int qi = wave; qi < nn; qi += 4) {
        Oh[(size_t)(start + qi) * DMODEL + h * HDIM + lane] = 0;
        if (lane == 0) {
          float2 mlv = {-FLT_MAX, 0.0f};
          *(float2*)(ml + ((size_t)(start + qi) * NHEAD + h) * 4 + 2) = mlv;
        }
      }
      return;
    }
    for (int qi = wave; qi < nn; qi += 4) {
      float qd = __bfloat162float(
          qkv[(size_t)(start + qi) * (3 * DMODEL) + h * HDIM + lane]);
      float sreg[8];
#pragma unroll
      for (int t = 0; t < 8; t++) {
        float sc = -FLT_MAX;
        if (t * 64 < nn) {
          int k = t * 64 + lane, kc = min(k, nn - 1);
          const __hip_bfloat16* Kr =
              qkv + (size_t)(start + kc) * (3 * DMODEL) + DMODEL + h * HDIM;
          float a = 0.f;
#pragma unroll
          for (int d = 0; d < 64; d++)
            a += __shfl(qd, d) * __bfloat162float(Kr[d]);
          if (k < nn) sc = a * scale;
        }
        sreg[t] = sc;
      }
      float m = -FLT_MAX;
#pragma unroll
      for (int t = 0; t < 8; t++) m = fmaxf(m, sreg[t]);
#pragma unroll
      for (int off = 32; off; off >>= 1) m = fmaxf(m, __shfl_xor(m, off));
      float lsum = 0.f;
#pragma unroll
      for (int t = 0; t < 8; t++) {
        float p = (sreg[t] == -FLT_MAX) ? 0.0f : __expf(sreg[t] - m);
        sreg[t] = p;
        lsum += p;
      }
#pragma unroll
      for (int off = 32; off; off >>= 1) lsum += __shfl_xor(lsum, off);
      float inv_l = 1.0f / lsum;
      float o = 0.f;
#pragma unroll
      for (int t = 0; t < 8; t++) {
        int kb = t * 64;
        if (kb < nn) {
          int kmax = min(64, nn - kb);
          const __hip_bfloat16* Vb = qkv + (size_t)(start + kb) * (3 * DMODEL) +
                                     2 * DMODEL + h * HDIM + lane;
          for (int j = 0; j < kmax; j++)
            o += __shfl(sreg[t], j) *
                 __bfloat162float(Vb[(size_t)j * (3 * DMODEL)]);
        }
      }
      Oh[(size_t)(start + qi) * DMODEL + h * HDIM + lane] = f2b(o * inv_l);
      if (lane == 0) {
        float2 mlv = {0.0f, 1.0f};
        *(float2*)(ml + ((size_t)(start + qi) * NHEAD + h) * 4) = mlv;
      }
    }
  }
}

// ---------------------------------------------------------------------------
// Merge the two key-half partials: out = (w1*O1 + w2*O2)/(w1*l1 + w2*l2),
// w_c = e^{m_c - max(m1,m2)}. One thread per (node, head, 8 dims).
__global__ __launch_bounds__(256) void merge_k(
    const __hip_bfloat16* __restrict__ O1, const __hip_bfloat16* __restrict__ O2,
    const float* __restrict__ ml, __hip_bfloat16* __restrict__ out) {
  int t = blockIdx.x * 256 + threadIdx.x;     // t < N_NODES*64
  int node = t >> 6;
  int rem = t & 63;
  int h = rem >> 3;
  int c8 = (rem & 7) * 8;
  float4 m4 = *(const float4*)(ml + ((size_t)node * NHEAD + h) * 4);
  float mm = fmaxf(m4.x, m4.z);
  float w1 = __expf(m4.x - mm), w2 = __expf(m4.z - mm);
  float inv = 1.0f / (w1 * m4.y + w2 * m4.w);
  size_t off = (size_t)node * DMODEL + h * HDIM + c8;
  ushort8 a = *(const ushort8*)((const unsigned short*)O1 + off);
  ushort8 b = *(const ushort8*)((const unsigned short*)O2 + off);
  ushort8 o;
#pragma unroll
  for (int i = 0; i < 8; i++)
    o[i] = f2b((w1 * b2f(a[i]) + w2 * b2f(b[i])) * inv);
  *(ushort8*)((unsigned short*)out + off) = o;
}

// ---------------------------------------------------------------------------
// Segment-mean pool, bf16 in, fp32 out. Grid (graphs, 2 col-chunks).
__global__ __launch_bounds__(256) void pool_k(
    const __hip_bfloat16* __restrict__ hp, const int* __restrict__ starts,
    float* __restrict__ pooled) {
  int g = blockIdx.x;
  int s0 = starts[g], s1 = starts[g + 1];
  s0 = min(max(s0, 0), N_NODES);
  s1 = min(max(s1, s0), N_NODES);
  int n = s1 - s0;
  float inv = n > 0 ? 1.0f / (float)n : 0.0f;
  int c = blockIdx.y * 256 + threadIdx.x;
  float acc = 0.f;
  for (int r = s0; r < s1; r++)
    acc += __bfloat162float(hp[(size_t)r * DMODEL + c]);
  pooled[(size_t)g * DMODEL + c] = acc * inv;
}

// ---------------------------------------------------------------------------
__global__ __launch_bounds__(256) void head2_k(
    const float* __restrict__ h1, const float* __restrict__ w2,
    const float* __restrict__ b2, float* __restrict__ y) {
  int row = blockIdx.x * 4 + (threadIdx.x >> 6);
  int lane = threadIdx.x & 63;
  float s = 0.f;
#pragma unroll
  for (int i = 0; i < 8; i++) {
    int c = lane + i * 64;
    s += h1[(size_t)row * DMODEL + c] * w2[c];
  }
#pragma unroll
  for (int off = 32; off; off >>= 1) s += __shfl_xor(s, off);
  if (lane == 0) y[row] = s + b2[0];
}

// ---------------------------------------------------------------------------
extern "C" void kernel_launch(void* const* d_in, const int* in_sizes, int n_in,
                              void* d_out, int out_size, void* d_ws,
                              size_t ws_size, hipStream_t stream) {
  const float* node_features = (const float*)d_in[0];
  const int* batch = (const int*)d_in[3];
  const float* emb_w = (const float*)d_in[4];
  const float* emb_b = (const float*)d_in[5];
  const float* in_proj_w = (const float*)d_in[6];
  const float* in_proj_b = (const float*)d_in[7];
  const float* out_w = (const float*)d_in[8];
  const float* out_b = (const float*)d_in[9];
  const float* ln1_g = (const float*)d_in[10];
  const float* ln1_b = (const float*)d_in[11];
  const float* ffn_w1 = (const float*)d_in[12];
  const float* ffn_b1 = (const float*)d_in[13];
  const float* ffn_w2 = (const float*)d_in[14];
  const float* ffn_b2 = (const float*)d_in[15];
  const float* ln2_g = (const float*)d_in[16];
  const float* ln2_b = (const float*)d_in[17];
  const float* head_w1 = (const float*)d_in[18];
  const float* head_b1 = (const float*)d_in[19];
  const float* head_w2 = (const float*)d_in[20];
  const float* head_b2 = (const float*)d_in[21];
  float* y = (float*)d_out;

  typedef __hip_bfloat16 bf;
  char* wsb = (char*)d_ws;
  int* starts = (int*)wsb;
  bf* nf_b = (bf*)(wsb + 1024);                        // N x 96
  bf* wq_b = nf_b + (size_t)N_NODES * D_INP;           // L x 1536 x 512
  bf* wo_b = wq_b + (size_t)NLAYER * 3 * DMODEL * DMODEL;
  bf* w1_b = wo_b + (size_t)NLAYER * DMODEL * DMODEL;
  bf* w2_b = w1_b + (size_t)NLAYER * DFF * DMODEL;
  bf* we_b = w2_b + (size_t)NLAYER * DMODEL * DFF;     // 512 x 96
  bf* hp   = we_b + (size_t)DMODEL * D_INP;            // N x 512
  bf* xb   = hp + (size_t)N_NODES * DMODEL;            // N x 512 (O2 half)
  bf* t1b  = xb + (size_t)N_NODES * DMODEL;            // N x 512 (O1 half / attn out)
  bf* qkvb = t1b + (size_t)N_NODES * DMODEL;           // N x 1536 (also ffn hidden)
  float* pooled = (float*)(qkvb + (size_t)N_NODES * 3 * DMODEL);
  float* h1 = pooled + (size_t)B_GRAPHS * DMODEL;
  float* ml = h1 + (size_t)B_GRAPHS * DMODEL;          // N x 8 x 4 floats

  starts_k<<<1, 256, 0, stream>>>(batch, starts);

  {
    int c4;
    c4 = NLAYER * 3 * DMODEL * DMODEL / 4;
    cvt_k<<<(c4 + 255) / 256, 256, 0, stream>>>(in_proj_w, wq_b, c4);
    c4 = NLAYER * DMODEL * DMODEL / 4;
    cvt_k<<<(c4 + 255) / 256, 256, 0, stream>>>(out_w, wo_b, c4);
    c4 = NLAYER * DFF * DMODEL / 4;
    cvt_k<<<(c4 + 255) / 256, 256, 0, stream>>>(ffn_w1, w1_b, c4);
    cvt_k<<<(c4 + 255) / 256, 256, 0, stream>>>(ffn_w2, w2_b, c4);
    padcvt_k<<<(N_NODES * D_INP + 255) / 256, 256, 0, stream>>>(node_features,
                                                                nf_b, N_NODES);
    padcvt_k<<<(DMODEL * D_INP + 255) / 256, 256, 0, stream>>>(emb_w, we_b,
                                                               DMODEL);
  }

  // embed: hp = nf @ emb_w^T + emb_b  (K=96, N=512 -> 2 col tiles)
  mgemm_k<<<(N_NODES / 128) * (DMODEL / 256), 256, 0, stream>>>(
      nf_b, we_b, emb_b, nullptr, hp, N_NODES, DMODEL, D_INP, 0);

  for (int l = 0; l < NLAYER; l++) {
    const bf* wq = wq_b + (size_t)l * 3 * DMODEL * DMODEL;
    const bf* wo = wo_b + (size_t)l * DMODEL * DMODEL;
    const bf* w1 = w1_b + (size_t)l * DFF * DMODEL;
    const bf* w2 = w2_b + (size_t)l * DMODEL * DFF;
    const float* ipb = in_proj_b + (size_t)l * 3 * DMODEL;
    const float* ob = out_b + (size_t)l * DMODEL;
    const float* b1 = ffn_b1 + (size_t)l * DFF;
    const float* b2 = ffn_b2 + (size_t)l * DMODEL;

    // qkv = hp @ in_proj^T + b  (N=1536 -> 6 col tiles)
    mgemm_k<<<(N_NODES / 128) * (3 * DMODEL / 256), 256, 0, stream>>>(
        hp, wq, ipb, nullptr, qkvb, N_NODES, 3 * DMODEL, DMODEL, 0);

    // attention halves -> t1b (half0) / xb (half1), then merge -> t1b
    attn5_k<<<B_GRAPHS * NHEAD * 2, 256, 0, stream>>>(qkvb, starts, t1b, xb, ml);
    merge_k<<<N_NODES * 64 / 256, 256, 0, stream>>>(t1b, xb, ml, t1b);

    // xb = t1b @ out_w^T + out_b + hp ; then LN in-place
    mgemm_k<<<(N_NODES / 128) * (DMODEL / 256), 256, 0, stream>>>(
        t1b, wo, ob, hp, xb, N_NODES, DMODEL, DMODEL, 0);
    lnb_k<<<N_NODES / 4, 256, 0, stream>>>(xb, ln1_g + l * DMODEL,
                                           ln1_b + l * DMODEL, xb);

    // FFN chunked through qkvb region (N*1536 bf16 == 18432*2048 bf16)
    const int CHUNK = 18432;
    for (int r0 = 0; r0 < N_NODES; r0 += CHUNK) {
      int rows = min(N_NODES - r0, CHUNK);
      bf* ffh = qkvb;
      mgemm_k<<<(rows / 128) * (DFF / 256), 256, 0, stream>>>(
          xb + (size_t)r0 * DMODEL, w1, b1, nullptr, ffh, rows, DFF, DMODEL, 1);
      mgemm_k<<<(rows / 128) * (DMODEL / 256), 256, 0, stream>>>(
          ffh, w2, b2, xb + (size_t)r0 * DMODEL, t1b + (size_t)r0 * DMODEL,
          rows, DMODEL, DFF, 0);
    }
    lnb_k<<<N_NODES / 4, 256, 0, stream>>>(t1b, ln2_g + l * DMODEL,
                                           ln2_b + l * DMODEL, hp);
  }

  pool_k<<<dim3(B_GRAPHS, 2), 256, 0, stream>>>(hp, starts, pooled);
  gemm_k<<<dim3(DMODEL / 64, B_GRAPHS / 64), 256, 0, stream>>>(
      pooled, head_w1, head_b1, nullptr, h1, B_GRAPHS, DMODEL, DMODEL, 2);
  head2_k<<<B_GRAPHS / 4, 256, 0, stream>>>(h1, head_w2, head_b2, y);
}

// Round 11
// 1398.392 us; speedup vs baseline: 1.2370x; 1.2370x over previous
//
#include <hip/hip_runtime.h>
#include <hip/hip_bf16.h>
#include <cstdint>
#include <cfloat>
#include <cstddef>
#include <type_traits>

#define N_NODES 24576
#define B_GRAPHS 128
#define D_IN 92
#define D_INP 96           // D_IN padded to multiple of 32 for MFMA K
#define DMODEL 512
#define NHEAD 8
#define HDIM 64
#define NLAYER 3
#define DFF 2048

typedef __attribute__((ext_vector_type(8))) short short8;
typedef __attribute__((ext_vector_type(4))) short short4v;
typedef __attribute__((ext_vector_type(8))) unsigned short ushort8;
typedef __attribute__((ext_vector_type(4))) float f32x4;

__device__ __forceinline__ float b2f(unsigned short u) {
  union { unsigned int i; float f; } x;
  x.i = ((unsigned int)u) << 16;
  return x.f;
}
__device__ __forceinline__ unsigned short f2b(float f) {
  __hip_bfloat16 h = __float2bfloat16(f);
  return *reinterpret_cast<unsigned short*>(&h);
}

// async global->LDS, 16B per lane; LDS dest = wave-uniform base + lane*16
__device__ __forceinline__ void gl2lds16(const __hip_bfloat16* g,
                                         __hip_bfloat16* l) {
  __builtin_amdgcn_global_load_lds(
      (const __attribute__((address_space(1))) unsigned int*)g,
      (__attribute__((address_space(3))) unsigned int*)l, 16, 0, 0);
}

// ---------------------------------------------------------------------------
// starts[g] = lower_bound(batch, g); handles int32 or int64 batch (sniffed).
__global__ void starts_k(const int* __restrict__ batch32, int* __restrict__ starts) {
  __shared__ int is64_s;
  const int tid = threadIdx.x;
  if (tid == 0) is64_s = 0;
  __syncthreads();
  int bad = 0;
  for (int i = tid; i < N_NODES - 1; i += 256)
    if (batch32[i] > batch32[i + 1]) bad = 1;
  if (bad) atomicOr(&is64_s, 1);
  __syncthreads();
  const int is64 = is64_s;
  if (tid <= B_GRAPHS) {
    int lo = 0, hi = N_NODES;
    while (lo < hi) {
      int mid = (lo + hi) >> 1;
      int v = is64 ? batch32[2 * mid] : batch32[mid];
      if (v < tid) lo = mid + 1; else hi = mid;
    }
    starts[tid] = lo;
  }
}

// ---------------------------------------------------------------------------
// fp32 -> bf16 flat convert (count multiple of 4)
__global__ __launch_bounds__(256) void cvt_k(const float* __restrict__ in,
                                             __hip_bfloat16* __restrict__ out,
                                             int count4) {
  int i = blockIdx.x * 256 + threadIdx.x;
  if (i < count4) {
    float4 v = ((const float4*)in)[i];
    short4v o;
    o[0] = (short)f2b(v.x); o[1] = (short)f2b(v.y);
    o[2] = (short)f2b(v.z); o[3] = (short)f2b(v.w);
    ((short4v*)out)[i] = o;
  }
}

// fp32 (rows x 92) -> bf16 (rows x 96), zero-padded tail
__global__ __launch_bounds__(256) void padcvt_k(const float* __restrict__ in,
                                                __hip_bfloat16* __restrict__ out,
                                                int rows) {
  int idx = blockIdx.x * 256 + threadIdx.x;
  if (idx < rows * D_INP) {
    int r = idx / D_INP, c = idx - r * D_INP;
    out[idx] = __float2bfloat16(c < D_IN ? in[(size_t)r * D_IN + c] : 0.0f);
  }
}

// ---------------------------------------------------------------------------
// bf16 MFMA GEMM (r9 configuration — measured best: 76 us FFN1a, 0 conflicts).
// C[m][n] = act( A[m][:] . W[n][:] + bias[n] + res[m][n] )
// A: MxK bf16 row-major, W: NxK bf16 row-major. M%128==0, N%128==0, K%32==0.
// 128x128 tile, BK=32, 256 threads = 4 waves (2x2 of 64x64 quadrants).
// Triple-buffered staging with raw `s_waitcnt vmcnt(4); s_barrier`.
// LDS chunk swizzle (r9-verified: conflicts 4.7M -> 0).
// 1D grid, XCD-aware swizzle (i%8 -> XCD): per-XCD contiguous row stripes.
__global__ __launch_bounds__(256) void mgemm_k(
    const __hip_bfloat16* __restrict__ A, const __hip_bfloat16* __restrict__ W,
    const float* __restrict__ bias, const __hip_bfloat16* __restrict__ res,
    __hip_bfloat16* __restrict__ C, int M, int N, int K, int act) {
  __shared__ __align__(16) __hip_bfloat16 As[3][128 * 32];
  __shared__ __align__(16) __hip_bfloat16 Ws[3][128 * 32];
  const int tid = threadIdx.x;
  const int wave = tid >> 6, lane = tid & 63;

  const int nxt = N >> 7, nmt = M >> 7;
  int rowt, colt;
  if ((nmt & 7) == 0) {
    const int rows_per = nmt >> 3;      // row tiles per XCD stripe
    const int x = blockIdx.x & 7;       // XCD (dispatch round-robin)
    const int j = blockIdx.x >> 3;
    rowt = x * rows_per + j % rows_per; // col-major within stripe
    colt = j / rows_per;
  } else {
    rowt = blockIdx.x / nxt;
    colt = blockIdx.x % nxt;
  }
  const int m0 = rowt * 128, n0 = colt * 128;

  const int mw = (wave >> 1) * 64, nw = (wave & 1) * 64;
  const int quad = lane >> 4, l16 = lane & 15;

  f32x4 acc[4][4] = {};

  // staging: wave stages rows [wave*32, wave*32+32); lane -> (r, p) with
  // r = lane>>2 (row in 16-group), p = lane&3 (LDS chunk slot). Source
  // chunk is swizzled: c = (p + (r>>1)) & 3.
  const int srow = wave * 32 + (lane >> 2);
  const int skc = (((lane & 3) + ((lane >> 2) >> 1)) & 3) * 8;
  const __hip_bfloat16* gA = A + (size_t)(m0 + srow) * K + skc;
  const __hip_bfloat16* gW = W + (size_t)(n0 + srow) * K + skc;
  const int lo = wave * 32 * 32;   // wave's slice offset within a buffer

  const int niter = K >> 5;
  // prologue: stage tiles 0 and 1
  gl2lds16(gA, &As[0][lo]);
  gl2lds16(gA + (size_t)16 * K, &As[0][lo + 16 * 32]);
  gl2lds16(gW, &Ws[0][lo]);
  gl2lds16(gW + (size_t)16 * K, &Ws[0][lo + 16 * 32]);
  if (niter > 1) {
    gl2lds16(gA + 32, &As[1][lo]);
    gl2lds16(gA + (size_t)16 * K + 32, &As[1][lo + 16 * 32]);
    gl2lds16(gW + 32, &Ws[1][lo]);
    gl2lds16(gW + (size_t)16 * K + 32, &Ws[1][lo + 16 * 32]);
  }

  // reader chunk position for this lane (row-mod-16 invariant)
  const int prd = ((quad - (l16 >> 1)) & 3) * 8;

  for (int it = 0; it < niter; ++it) {
    // wait for tile `it` only (4 of our loads); keep tile it+1 in flight.
    if (it + 1 < niter)
      asm volatile("s_waitcnt vmcnt(4)\n\ts_barrier" ::: "memory");
    else
      asm volatile("s_waitcnt vmcnt(0)\n\ts_barrier" ::: "memory");
    // prefetch tile it+2 into the buffer last read at iter it-1 (all waves
    // finished those reads before this barrier).
    if (it + 2 < niter) {
      const int kpre = (it + 2) * 32;
      const int nb = (it + 2) % 3;
      gl2lds16(gA + kpre, &As[nb][lo]);
      gl2lds16(gA + (size_t)16 * K + kpre, &As[nb][lo + 16 * 32]);
      gl2lds16(gW + kpre, &Ws[nb][lo]);
      gl2lds16(gW + (size_t)16 * K + kpre, &Ws[nb][lo + 16 * 32]);
    }
    const int cb = it % 3;
    short8 af[4], bf[4];
#pragma unroll
    for (int t = 0; t < 4; t++) {
      af[t] = *(const short8*)&As[cb][(mw + t * 16 + l16) * 32 + prd];
      bf[t] = *(const short8*)&Ws[cb][(nw + t * 16 + l16) * 32 + prd];
    }
#pragma unroll
    for (int mt = 0; mt < 4; mt++)
#pragma unroll
      for (int nt = 0; nt < 4; nt++)
        acc[mt][nt] = __builtin_amdgcn_mfma_f32_16x16x32_bf16(
            af[mt], bf[nt], acc[mt][nt], 0, 0, 0);
  }

#pragma unroll
  for (int mt = 0; mt < 4; mt++) {
#pragma unroll
    for (int nt = 0; nt < 4; nt++) {
      const int n = n0 + nw + nt * 16 + l16;
      const float bv = bias[n];
#pragma unroll
      for (int i = 0; i < 4; i++) {
        const int m = m0 + mw + mt * 16 + quad * 4 + i;
        float v = acc[mt][nt][i] + bv;
        if (res) v += __bfloat162float(res[(size_t)m * N + n]);
        if (act == 1) v = fmaxf(v, 0.0f);
        C[(size_t)m * N + n] = __float2bfloat16(v);
      }
    }
  }
}

// ---------------------------------------------------------------------------
// fp32 SIMT GEMM (kept for the tiny head): 64x64 tile.
__global__ __launch_bounds__(256) void gemm_k(
    const float* __restrict__ A, const float* __restrict__ W,
    const float* __restrict__ bias, const float* __restrict__ res,
    float* __restrict__ C, int M, int N, int K, int act) {
  __shared__ float As[16][68];
  __shared__ float Ws[16][68];
  const int tid = threadIdx.x;
  const int tx = tid & 15, ty = tid >> 4;
  const int m0 = blockIdx.y * 64, n0 = blockIdx.x * 64;
  const int lr = tid >> 2;
  const int lk = (tid & 3) * 4;
  float acc[4][4] = {{0.f}};
  for (int k0 = 0; k0 < K; k0 += 16) {
#pragma unroll
    for (int i = 0; i < 4; i++) {
      int k = k0 + lk + i;
      As[lk + i][lr] = (k < K) ? A[(size_t)(m0 + lr) * K + k] : 0.0f;
      Ws[lk + i][lr] = (k < K) ? W[(size_t)(n0 + lr) * K + k] : 0.0f;
    }
    __syncthreads();
#pragma unroll
    for (int kk = 0; kk < 16; kk++) {
      float4 a4 = *(const float4*)&As[kk][ty * 4];
      float4 w4 = *(const float4*)&Ws[kk][tx * 4];
      float a[4] = {a4.x, a4.y, a4.z, a4.w};
      float w[4] = {w4.x, w4.y, w4.z, w4.w};
#pragma unroll
      for (int i = 0; i < 4; i++)
#pragma unroll
        for (int j = 0; j < 4; j++) acc[i][j] += a[i] * w[j];
    }
    __syncthreads();
  }
#pragma unroll
  for (int i = 0; i < 4; i++) {
    int m = m0 + ty * 4 + i;
#pragma unroll
    for (int j = 0; j < 4; j++) {
      int n = n0 + tx * 4 + j;
      float v = acc[i][j] + bias[n];
      if (res) v += res[(size_t)m * N + n];
      if (act == 1) v = fmaxf(v, 0.0f);
      else if (act == 2) v = v / (1.0f + __expf(-v));
      C[(size_t)m * N + n] = v;
    }
  }
}

// ---------------------------------------------------------------------------
// Row LayerNorm over D=512, bf16 in/out, fp32 params. 4 rows/block.
__global__ __launch_bounds__(256) void lnb_k(
    const __hip_bfloat16* __restrict__ in, const float* __restrict__ g,
    const float* __restrict__ b, __hip_bfloat16* __restrict__ out) {
  int row = blockIdx.x * 4 + (threadIdx.x >> 6);
  int lane = threadIdx.x & 63;
  const unsigned short* rp =
      (const unsigned short*)in + (size_t)row * DMODEL + lane * 8;
  ushort8 sv = *(const ushort8*)rp;
  float v[8];
  float s = 0.f;
#pragma unroll
  for (int i = 0; i < 8; i++) { v[i] = b2f(sv[i]); s += v[i]; }
#pragma unroll
  for (int off = 32; off; off >>= 1) s += __shfl_xor(s, off);
  float mu = s * (1.0f / DMODEL);
  float vs = 0.f;
#pragma unroll
  for (int i = 0; i < 8; i++) { float d = v[i] - mu; vs += d * d; }
#pragma unroll
  for (int off = 32; off; off >>= 1) vs += __shfl_xor(vs, off);
  float rs = rsqrtf(vs * (1.0f / DMODEL) + 1e-5f);
  ushort8 o;
#pragma unroll
  for (int i = 0; i < 8; i++) {
    int c = lane * 8 + i;
    o[i] = f2b((v[i] - mu) * rs * g[c] + b[c]);
  }
  *(ushort8*)((unsigned short*)out + (size_t)row * DMODEL + lane * 8) = o;
}

// ---------------------------------------------------------------------------
// MFMA ragged attention, key-split flash halves.
// Block = (graph, head, key-half); 4 waves. Each half computes, for EVERY
// query q of the graph: O'[q] = sum_{k in half} e^{s_qk - m_half} V_k (bf16,
// unnormalized) plus (m_half, l_half) into ml[]. merge_k renormalizes.
// LDS: Ks[128][72] + Vt[64][136] + Ps[4][16][136] = 52 KB -> 3 blocks/CU.
// Ps ordering fence is lgkmcnt-only (wave-local LDS W->R): the old
// __threadfence_block() emitted vmcnt(0) too, draining the scattered O-partial
// stores every iteration (suspected cause of VALUBusy~0.1% idle profile).
#define MAXNH 128
__global__ __launch_bounds__(256, 3) void attn5_k(
    const __hip_bfloat16* __restrict__ qkv, const int* __restrict__ starts,
    __hip_bfloat16* __restrict__ O1, __hip_bfloat16* __restrict__ O2,
    float* __restrict__ ml) {
  const int half = blockIdx.x & 1;
  const int gh = blockIdx.x >> 1;
  const int g = gh >> 3, h = gh & 7;
  int s0 = starts[g], s1 = starts[g + 1];
  s0 = min(max(s0, 0), N_NODES);
  s1 = min(max(s1, s0), N_NODES);
  const int n = s1 - s0, start = s0;
  if (n == 0) return;
  const int tid = threadIdx.x, wave = tid >> 6, lane = tid & 63;
  const int quad = lane >> 4, l16 = lane & 15;
  unsigned short* Oh = (unsigned short*)(half ? O2 : O1);

  __shared__ __align__(16) unsigned short Ks[128][72];     // K rows [key][d]
  __shared__ __align__(16) unsigned short Vt[64][136];     // V^T [d][key]
  __shared__ __align__(16) unsigned short Ps[4][16][136];  // per-wave P[q][key]

  if (n <= 2 * MAXNH) {
    const int nh1 = (n + 1) >> 1;
    const int k0g = half * nh1;                 // this half's first key
    const int nh = half ? (n - nh1) : nh1;      // this half's key count
    const int ktq = (n + 15) >> 4;              // query tiles (full n)

    if (nh == 0) {  // empty half (n==1): emit zero partials for all queries
      for (int mt = wave; mt < ktq; mt += 4) {
        const int q = mt * 16 + l16;
        if (q < n) {
          short4v z = {0, 0, 0, 0};
#pragma unroll
          for (int dt = 0; dt < 4; dt++)
            *(short4v*)(Oh + (size_t)(start + q) * DMODEL + h * HDIM +
                        dt * 16 + quad * 4) = z;
          if (quad == 0) {
            float2 mlv = {-FLT_MAX, 0.0f};
            *(float2*)(ml + ((size_t)(start + q) * NHEAD + h) * 4 + half * 2) = mlv;
          }
        }
      }
      return;
    }

    // ---- stage K rows of this half ----
    for (int idx = tid; idx < nh * 8; idx += 256) {
      int r = idx >> 3, c = (idx & 7) * 8;
      *(ushort8*)&Ks[r][c] = *(const ushort8*)((const unsigned short*)qkv +
                                               (size_t)(start + k0g + r) * 1536 +
                                               512 + h * HDIM + c);
    }
    // zero K pad rows [nh, min(128, nh+16))
    for (int idx = tid; idx < 16 * 8; idx += 256) {
      int r = nh + (idx >> 3), c = (idx & 7) * 8;
      if (r < 128) {
        ushort8 z = {0, 0, 0, 0, 0, 0, 0, 0};
        *(ushort8*)&Ks[r][c] = z;
      }
    }
    // ---- stage V transposed: Vt[d][r] = V[k0g+r][d] ----
    const int vr = tid & 31, dc8 = tid >> 5;
    for (int r0 = 0; r0 < nh; r0 += 32) {
      int r = r0 + vr;
      if (r < nh) {
        ushort8 v = *(const ushort8*)((const unsigned short*)qkv +
                                      (size_t)(start + k0g + r) * 1536 + 1024 +
                                      h * HDIM + dc8 * 8);
#pragma unroll
        for (int j = 0; j < 8; j++) Vt[dc8 * 8 + j][r] = v[j];
      }
    }
    // zero key cols [nh, nh+32)
    for (int idx = tid; idx < 64 * 32; idx += 256) {
      int d = idx >> 5, r = nh + (idx & 31);
      if (r < 136) Vt[d][r] = 0;
    }
    __syncthreads();

    const int ktmax2 = (nh + 15) >> 4;  // key tiles in this half (<=8)
    const int nkc2 = (nh + 31) >> 5;    // 32-wide key chunks (<=4)
    const float scale = 0.125f;

    for (int mt = wave; mt < ktq; mt += 4) {
      // Q fragments: lane l16 = q, dims quad*8..+7 per 32-chunk
      const int qrow = start + min(mt * 16 + l16, n - 1);
      const short8 qf0 = *(const short8*)((const unsigned short*)qkv +
                                          (size_t)qrow * 1536 + h * HDIM + quad * 8);
      const short8 qf1 = *(const short8*)((const unsigned short*)qkv +
                                          (size_t)qrow * 1536 + h * HDIM + 32 + quad * 8);
      f32x4 sacc[8];
      // ---- scores: S^T[key][q] = K . Q^T (K-frags from LDS) ----
#pragma unroll
      for (int kt = 0; kt < 8; kt++) {
        if (kt < ktmax2) {
          const int krow = kt * 16 + l16;
          const short8 kf0 = *(const short8*)&Ks[krow][quad * 8];
          const short8 kf1 = *(const short8*)&Ks[krow][32 + quad * 8];
          f32x4 a = {0.f, 0.f, 0.f, 0.f};
          a = __builtin_amdgcn_mfma_f32_16x16x32_bf16(kf0, qf0, a, 0, 0, 0);
          a = __builtin_amdgcn_mfma_f32_16x16x32_bf16(kf1, qf1, a, 0, 0, 0);
          sacc[kt] = a;
        }
      }
      // ---- local softmax stats for q = l16 over this half's keys ----
      float mx = -FLT_MAX;
#pragma unroll
      for (int kt = 0; kt < 8; kt++) {
        if (kt < ktmax2) {
#pragma unroll
          for (int i = 0; i < 4; i++) {
            const int key = kt * 16 + quad * 4 + i;
            const float v = sacc[kt][i] * scale;
            sacc[kt][i] = v;
            if (key < nh) mx = fmaxf(mx, v);
          }
        }
      }
      mx = fmaxf(mx, __shfl_xor(mx, 16));
      mx = fmaxf(mx, __shfl_xor(mx, 32));
      float ls = 0.f;
#pragma unroll
      for (int kt = 0; kt < 8; kt++) {
        if (kt < ktmax2) {
#pragma unroll
          for (int i = 0; i < 4; i++) {
            const int key = kt * 16 + quad * 4 + i;
            const float p = (key < nh) ? __expf(sacc[kt][i] - mx) : 0.0f;
            sacc[kt][i] = p;
            ls += p;
          }
        }
      }
      ls += __shfl_xor(ls, 16);
      ls += __shfl_xor(ls, 32);
      // ---- store UNNORMALIZED p (bf16) to Ps; zero kt in [ktmax2, 2*nkc2) ----
#pragma unroll
      for (int kt = 0; kt < 8; kt++) {
        if (kt < 2 * nkc2) {
          short4v pp;
#pragma unroll
          for (int i = 0; i < 4; i++) {
            const float p = (kt < ktmax2) ? sacc[kt][i] : 0.0f;
            pp[i] = (short)f2b(p);
          }
          *(short4v*)&Ps[wave][l16][kt * 16 + quad * 4] = pp;
        }
      }
      // wave-local LDS write->read ordering: lgkm-only (no vmcnt drain)
      asm volatile("s_waitcnt lgkmcnt(0)" ::: "memory");
      // ---- PV: O'[d][q] = sum_key V^T[d][key] * p[q][key] ----
      const int qv = mt * 16 + l16;
#pragma unroll
      for (int dt = 0; dt < 4; dt++) {
        f32x4 oa = {0.f, 0.f, 0.f, 0.f};
#pragma unroll
        for (int kc = 0; kc < 4; kc++) {
          if (kc < nkc2) {
            const short8 vf = *(const short8*)&Vt[dt * 16 + l16][kc * 32 + quad * 8];
            const short8 pf = *(const short8*)&Ps[wave][l16][kc * 32 + quad * 8];
            oa = __builtin_amdgcn_mfma_f32_16x16x32_bf16(vf, pf, oa, 0, 0, 0);
          }
        }
        if (qv < n) {
          short4v ov;
#pragma unroll
          for (int i = 0; i < 4; i++) ov[i] = (short)f2b(oa[i]);
          *(short4v*)(Oh + (size_t)(start + qv) * DMODEL + h * HDIM +
                      dt * 16 + quad * 4) = ov;
        }
      }
      if (qv < n && quad == 0) {
        float2 mlv = {mx, ls};
        *(float2*)(ml + ((size_t)(start + qv) * NHEAD + h) * 4 + half * 2) = mlv;
      }
    }
  } else {
    // fallback (n in (256,512]; statistically never). half 0 computes the
    // full normalized attention -> O1, ml=(0,1); half 1 emits zero partials.
    const float scale = 0.125f;
    int nn = min(n, 512);
    if (half == 1) {
      for (int qi = wave; qi < nn; qi += 4) {
        Oh[(size_t)(start + qi) * DMODEL + h * HDIM + lane] = 0;
        if (lane == 0) {
          float2 mlv = {-FLT_MAX, 0.0f};
          *(float2*)(ml + ((size_t)(start + qi) * NHEAD + h) * 4 + 2) = mlv;
        }
      }
      return;
    }
    for (int qi = wave; qi < nn; qi += 4) {
      float qd = __bfloat162float(
          qkv[(size_t)(start + qi) * (3 * DMODEL) + h * HDIM + lane]);
      float sreg[8];
#pragma unroll
      for (int t = 0; t < 8; t++) {
        float sc = -FLT_MAX;
        if (t * 64 < nn) {
          int k = t * 64 + lane, kc = min(k, nn - 1);
          const __hip_bfloat16* Kr =
              qkv + (size_t)(start + kc) * (3 * DMODEL) + DMODEL + h * HDIM;
          float a = 0.f;
#pragma unroll
          for (int d = 0; d < 64; d++)
            a += __shfl(qd, d) * __bfloat162float(Kr[d]);
          if (k < nn) sc = a * scale;
        }
        sreg[t] = sc;
      }
      float m = -FLT_MAX;
#pragma unroll
      for (int t = 0; t < 8; t++) m = fmaxf(m, sreg[t]);
#pragma unroll
      for (int off = 32; off; off >>= 1) m = fmaxf(m, __shfl_xor(m, off));
      float lsum = 0.f;
#pragma unroll
      for (int t = 0; t < 8; t++) {
        float p = (sreg[t] == -FLT_MAX) ? 0.0f : __expf(sreg[t] - m);
        sreg[t] = p;
        lsum += p;
      }
#pragma unroll
      for (int off = 32; off; off >>= 1) lsum += __shfl_xor(lsum, off);
      float inv_l = 1.0f / lsum;
      float o = 0.f;
#pragma unroll
      for (int t = 0; t < 8; t++) {
        int kb = t * 64;
        if (kb < nn) {
          int kmax = min(64, nn - kb);
          const __hip_bfloat16* Vb = qkv + (size_t)(start + kb) * (3 * DMODEL) +
                                     2 * DMODEL + h * HDIM + lane;
          for (int j = 0; j < kmax; j++)
            o += __shfl(sreg[t], j) *
                 __bfloat162float(Vb[(size_t)j * (3 * DMODEL)]);
        }
      }
      Oh[(size_t)(start + qi) * DMODEL + h * HDIM + lane] = f2b(o * inv_l);
      if (lane == 0) {
        float2 mlv = {0.0f, 1.0f};
        *(float2*)(ml + ((size_t)(start + qi) * NHEAD + h) * 4) = mlv;
      }
    }
  }
}

// ---------------------------------------------------------------------------
// Merge the two key-half partials: out = (w1*O1 + w2*O2)/(w1*l1 + w2*l2),
// w_c = e^{m_c - max(m1,m2)}. One thread per (node, head, 8 dims).
__global__ __launch_bounds__(256) void merge_k(
    const __hip_bfloat16* __restrict__ O1, const __hip_bfloat16* __restrict__ O2,
    const float* __restrict__ ml, __hip_bfloat16* __restrict__ out) {
  int t = blockIdx.x * 256 + threadIdx.x;     // t < N_NODES*64
  int node = t >> 6;
  int rem = t & 63;
  int h = rem >> 3;
  int c8 = (rem & 7) * 8;
  float4 m4 = *(const float4*)(ml + ((size_t)node * NHEAD + h) * 4);
  float mm = fmaxf(m4.x, m4.z);
  float w1 = __expf(m4.x - mm), w2 = __expf(m4.z - mm);
  float inv = 1.0f / (w1 * m4.y + w2 * m4.w);
  size_t off = (size_t)node * DMODEL + h * HDIM + c8;
  ushort8 a = *(const ushort8*)((const unsigned short*)O1 + off);
  ushort8 b = *(const ushort8*)((const unsigned short*)O2 + off);
  ushort8 o;
#pragma unroll
  for (int i = 0; i < 8; i++)
    o[i] = f2b((w1 * b2f(a[i]) + w2 * b2f(b[i])) * inv);
  *(ushort8*)((unsigned short*)out + off) = o;
}

// ---------------------------------------------------------------------------
// Segment-mean pool, bf16 in, fp32 out. Grid (graphs, 2 col-chunks).
__global__ __launch_bounds__(256) void pool_k(
    const __hip_bfloat16* __restrict__ hp, const int* __restrict__ starts,
    float* __restrict__ pooled) {
  int g = blockIdx.x;
  int s0 = starts[g], s1 = starts[g + 1];
  s0 = min(max(s0, 0), N_NODES);
  s1 = min(max(s1, s0), N_NODES);
  int n = s1 - s0;
  float inv = n > 0 ? 1.0f / (float)n : 0.0f;
  int c = blockIdx.y * 256 + threadIdx.x;
  float acc = 0.f;
  for (int r = s0; r < s1; r++)
    acc += __bfloat162float(hp[(size_t)r * DMODEL + c]);
  pooled[(size_t)g * DMODEL + c] = acc * inv;
}

// ---------------------------------------------------------------------------
__global__ __launch_bounds__(256) void head2_k(
    const float* __restrict__ h1, const float* __restrict__ w2,
    const float* __restrict__ b2, float* __restrict__ y) {
  int row = blockIdx.x * 4 + (threadIdx.x >> 6);
  int lane = threadIdx.x & 63;
  float s = 0.f;
#pragma unroll
  for (int i = 0; i < 8; i++) {
    int c = lane + i * 64;
    s += h1[(size_t)row * DMODEL + c] * w2[c];
  }
#pragma unroll
  for (int off = 32; off; off >>= 1) s += __shfl_xor(s, off);
  if (lane == 0) y[row] = s + b2[0];
}

// ---------------------------------------------------------------------------
extern "C" void kernel_launch(void* const* d_in, const int* in_sizes, int n_in,
                              void* d_out, int out_size, void* d_ws,
                              size_t ws_size, hipStream_t stream) {
  const float* node_features = (const float*)d_in[0];
  const int* batch = (const int*)d_in[3];
  const float* emb_w = (const float*)d_in[4];
  const float* emb_b = (const float*)d_in[5];
  const float* in_proj_w = (const float*)d_in[6];
  const float* in_proj_b = (const float*)d_in[7];
  const float* out_w = (const float*)d_in[8];
  const float* out_b = (const float*)d_in[9];
  const float* ln1_g = (const float*)d_in[10];
  const float* ln1_b = (const float*)d_in[11];
  const float* ffn_w1 = (const float*)d_in[12];
  const float* ffn_b1 = (const float*)d_in[13];
  const float* ffn_w2 = (const float*)d_in[14];
  const float* ffn_b2 = (const float*)d_in[15];
  const float* ln2_g = (const float*)d_in[16];
  const float* ln2_b = (const float*)d_in[17];
  const float* head_w1 = (const float*)d_in[18];
  const float* head_b1 = (const float*)d_in[19];
  const float* head_w2 = (const float*)d_in[20];
  const float* head_b2 = (const float*)d_in[21];
  float* y = (float*)d_out;

  typedef __hip_bfloat16 bf;
  char* wsb = (char*)d_ws;
  int* starts = (int*)wsb;
  bf* nf_b = (bf*)(wsb + 1024);                        // N x 96
  bf* wq_b = nf_b + (size_t)N_NODES * D_INP;           // L x 1536 x 512
  bf* wo_b = wq_b + (size_t)NLAYER * 3 * DMODEL * DMODEL;
  bf* w1_b = wo_b + (size_t)NLAYER * DMODEL * DMODEL;
  bf* w2_b = w1_b + (size_t)NLAYER * DFF * DMODEL;
  bf* we_b = w2_b + (size_t)NLAYER * DMODEL * DFF;     // 512 x 96
  bf* hp   = we_b + (size_t)DMODEL * D_INP;            // N x 512
  bf* xb   = hp + (size_t)N_NODES * DMODEL;            // N x 512 (O2 half)
  bf* t1b  = xb + (size_t)N_NODES * DMODEL;            // N x 512 (O1 half / attn out)
  bf* qkvb = t1b + (size_t)N_NODES * DMODEL;           // N x 1536 (also ffn hidden)
  float* pooled = (float*)(qkvb + (size_t)N_NODES * 3 * DMODEL);
  float* h1 = pooled + (size_t)B_GRAPHS * DMODEL;
  float* ml = h1 + (size_t)B_GRAPHS * DMODEL;          // N x 8 x 4 floats

  starts_k<<<1, 256, 0, stream>>>(batch, starts);

  {
    int c4;
    c4 = NLAYER * 3 * DMODEL * DMODEL / 4;
    cvt_k<<<(c4 + 255) / 256, 256, 0, stream>>>(in_proj_w, wq_b, c4);
    c4 = NLAYER * DMODEL * DMODEL / 4;
    cvt_k<<<(c4 + 255) / 256, 256, 0, stream>>>(out_w, wo_b, c4);
    c4 = NLAYER * DFF * DMODEL / 4;
    cvt_k<<<(c4 + 255) / 256, 256, 0, stream>>>(ffn_w1, w1_b, c4);
    cvt_k<<<(c4 + 255) / 256, 256, 0, stream>>>(ffn_w2, w2_b, c4);
    padcvt_k<<<(N_NODES * D_INP + 255) / 256, 256, 0, stream>>>(node_features,
                                                                nf_b, N_NODES);
    padcvt_k<<<(DMODEL * D_INP + 255) / 256, 256, 0, stream>>>(emb_w, we_b,
                                                               DMODEL);
  }

  // embed: hp = nf @ emb_w^T + emb_b  (K=96)
  mgemm_k<<<(N_NODES / 128) * (DMODEL / 128), 256, 0, stream>>>(
      nf_b, we_b, emb_b, nullptr, hp, N_NODES, DMODEL, D_INP, 0);

  for (int l = 0; l < NLAYER; l++) {
    const bf* wq = wq_b + (size_t)l * 3 * DMODEL * DMODEL;
    const bf* wo = wo_b + (size_t)l * DMODEL * DMODEL;
    const bf* w1 = w1_b + (size_t)l * DFF * DMODEL;
    const bf* w2 = w2_b + (size_t)l * DMODEL * DFF;
    const float* ipb = in_proj_b + (size_t)l * 3 * DMODEL;
    const float* ob = out_b + (size_t)l * DMODEL;
    const float* b1 = ffn_b1 + (size_t)l * DFF;
    const float* b2 = ffn_b2 + (size_t)l * DMODEL;

    // qkv = hp @ in_proj^T + b
    mgemm_k<<<(N_NODES / 128) * (3 * DMODEL / 128), 256, 0, stream>>>(
        hp, wq, ipb, nullptr, qkvb, N_NODES, 3 * DMODEL, DMODEL, 0);

    // attention halves -> t1b (half0) / xb (half1), then merge -> t1b
    attn5_k<<<B_GRAPHS * NHEAD * 2, 256, 0, stream>>>(qkvb, starts, t1b, xb, ml);
    merge_k<<<N_NODES * 64 / 256, 256, 0, stream>>>(t1b, xb, ml, t1b);

    // xb = t1b @ out_w^T + out_b + hp ; then LN in-place
    mgemm_k<<<(N_NODES / 128) * (DMODEL / 128), 256, 0, stream>>>(
        t1b, wo, ob, hp, xb, N_NODES, DMODEL, DMODEL, 0);
    lnb_k<<<N_NODES / 4, 256, 0, stream>>>(xb, ln1_g + l * DMODEL,
                                           ln1_b + l * DMODEL, xb);

    // FFN chunked through qkvb region (N*1536 bf16 == 18432*2048 bf16)
    const int CHUNK = 18432;
    for (int r0 = 0; r0 < N_NODES; r0 += CHUNK) {
      int rows = min(N_NODES - r0, CHUNK);
      bf* ffh = qkvb;
      mgemm_k<<<(rows / 128) * (DFF / 128), 256, 0, stream>>>(
          xb + (size_t)r0 * DMODEL, w1, b1, nullptr, ffh, rows, DFF, DMODEL, 1);
      mgemm_k<<<(rows / 128) * (DMODEL / 128), 256, 0, stream>>>(
          ffh, w2, b2, xb + (size_t)r0 * DMODEL, t1b + (size_t)r0 * DMODEL,
          rows, DMODEL, DFF, 0);
    }
    lnb_k<<<N_NODES / 4, 256, 0, stream>>>(t1b, ln2_g + l * DMODEL,
                                           ln2_b + l * DMODEL, hp);
  }

  pool_k<<<dim3(B_GRAPHS, 2), 256, 0, stream>>>(hp, starts, pooled);
  gemm_k<<<dim3(DMODEL / 64, B_GRAPHS / 64), 256, 0, stream>>>(
      pooled, head_w1, head_b1, nullptr, h1, B_GRAPHS, DMODEL, DMODEL, 2);
  head2_k<<<B_GRAPHS / 4, 256, 0, stream>>>(h1, head_w2, head_b2, y);
}

// Round 12
// 1166.485 us; speedup vs baseline: 1.4830x; 1.1988x over previous
//
#include <hip/hip_runtime.h>
#include <hip/hip_bf16.h>
#include <cstdint>
#include <cfloat>
#include <cstddef>
#include <type_traits>

#define N_NODES 24576
#define B_GRAPHS 128
#define D_IN 92
#define D_INP 96           // D_IN padded to multiple of 32 for MFMA K
#define DMODEL 512
#define NHEAD 8
#define HDIM 64
#define NLAYER 3
#define DFF 2048

typedef __attribute__((ext_vector_type(8))) short short8;
typedef __attribute__((ext_vector_type(4))) short short4v;
typedef __attribute__((ext_vector_type(8))) unsigned short ushort8;
typedef __attribute__((ext_vector_type(4))) float f32x4;

__device__ __forceinline__ float b2f(unsigned short u) {
  union { unsigned int i; float f; } x;
  x.i = ((unsigned int)u) << 16;
  return x.f;
}
__device__ __forceinline__ unsigned short f2b(float f) {
  __hip_bfloat16 h = __float2bfloat16(f);
  return *reinterpret_cast<unsigned short*>(&h);
}

// async global->LDS, 16B per lane; LDS dest = wave-uniform base + lane*16
__device__ __forceinline__ void gl2lds16(const __hip_bfloat16* g,
                                         __hip_bfloat16* l) {
  __builtin_amdgcn_global_load_lds(
      (const __attribute__((address_space(1))) unsigned int*)g,
      (__attribute__((address_space(3))) unsigned int*)l, 16, 0, 0);
}

// ---------------------------------------------------------------------------
// starts[g] = lower_bound(batch, g); handles int32 or int64 batch (sniffed).
__global__ void starts_k(const int* __restrict__ batch32, int* __restrict__ starts) {
  __shared__ int is64_s;
  const int tid = threadIdx.x;
  if (tid == 0) is64_s = 0;
  __syncthreads();
  int bad = 0;
  for (int i = tid; i < N_NODES - 1; i += 256)
    if (batch32[i] > batch32[i + 1]) bad = 1;
  if (bad) atomicOr(&is64_s, 1);
  __syncthreads();
  const int is64 = is64_s;
  if (tid <= B_GRAPHS) {
    int lo = 0, hi = N_NODES;
    while (lo < hi) {
      int mid = (lo + hi) >> 1;
      int v = is64 ? batch32[2 * mid] : batch32[mid];
      if (v < tid) lo = mid + 1; else hi = mid;
    }
    starts[tid] = lo;
  }
}

// ---------------------------------------------------------------------------
// fp32 -> bf16 flat convert (count multiple of 4)
__global__ __launch_bounds__(256) void cvt_k(const float* __restrict__ in,
                                             __hip_bfloat16* __restrict__ out,
                                             int count4) {
  int i = blockIdx.x * 256 + threadIdx.x;
  if (i < count4) {
    float4 v = ((const float4*)in)[i];
    short4v o;
    o[0] = (short)f2b(v.x); o[1] = (short)f2b(v.y);
    o[2] = (short)f2b(v.z); o[3] = (short)f2b(v.w);
    ((short4v*)out)[i] = o;
  }
}

// fp32 (rows x 92) -> bf16 (rows x 96), zero-padded tail
__global__ __launch_bounds__(256) void padcvt_k(const float* __restrict__ in,
                                                __hip_bfloat16* __restrict__ out,
                                                int rows) {
  int idx = blockIdx.x * 256 + threadIdx.x;
  if (idx < rows * D_INP) {
    int r = idx / D_INP, c = idx - r * D_INP;
    out[idx] = __float2bfloat16(c < D_IN ? in[(size_t)r * D_IN + c] : 0.0f);
  }
}

// ---------------------------------------------------------------------------
// bf16 MFMA GEMM (r9 K-loop + vectorized epilogue).
// C[m][n] = act( A[m][:] . W[n][:] + bias[n] + res[m][n] )
// A: MxK bf16 row-major, W: NxK bf16 row-major. M%128==0, N%128==0, K%32==0.
// 128x128 tile, BK=32, 256 threads = 4 waves (2x2 of 64x64 quadrants).
// Triple-buffered staging with raw `s_waitcnt vmcnt(4); s_barrier`.
// LDS chunk swizzle (r9-verified: SQ_LDS_BANK_CONFLICT 4.7M -> 0).
// Epilogue: acc+bias staged fp32 through the (now free) K-loop LDS in 2
// passes of 32 rows per wave; readback row-major; res added via ushort8
// vector loads; ushort8 stores (8x128B segments/instr vs 64 scalar stores).
// 1D grid, XCD-aware swizzle (i%8 -> XCD): per-XCD contiguous row stripes.
__global__ __launch_bounds__(256) void mgemm_k(
    const __hip_bfloat16* __restrict__ A, const __hip_bfloat16* __restrict__ W,
    const float* __restrict__ bias, const __hip_bfloat16* __restrict__ res,
    __hip_bfloat16* __restrict__ C, int M, int N, int K, int act) {
  __shared__ __align__(16) __hip_bfloat16 As[3][128 * 32];
  __shared__ __align__(16) __hip_bfloat16 Ws[3][128 * 32];
  const int tid = threadIdx.x;
  const int wave = tid >> 6, lane = tid & 63;

  const int nxt = N >> 7, nmt = M >> 7;
  int rowt, colt;
  if ((nmt & 7) == 0) {
    const int rows_per = nmt >> 3;      // row tiles per XCD stripe
    const int x = blockIdx.x & 7;       // XCD (dispatch round-robin)
    const int j = blockIdx.x >> 3;
    rowt = x * rows_per + j % rows_per; // col-major within stripe
    colt = j / rows_per;
  } else {
    rowt = blockIdx.x / nxt;
    colt = blockIdx.x % nxt;
  }
  const int m0 = rowt * 128, n0 = colt * 128;

  const int mw = (wave >> 1) * 64, nw = (wave & 1) * 64;
  const int quad = lane >> 4, l16 = lane & 15;

  f32x4 acc[4][4] = {};

  // staging: wave stages rows [wave*32, wave*32+32); lane -> (r, p) with
  // r = lane>>2 (row in 16-group), p = lane&3 (LDS chunk slot). Source
  // chunk is swizzled: c = (p + (r>>1)) & 3.
  const int srow = wave * 32 + (lane >> 2);
  const int skc = (((lane & 3) + ((lane >> 2) >> 1)) & 3) * 8;
  const __hip_bfloat16* gA = A + (size_t)(m0 + srow) * K + skc;
  const __hip_bfloat16* gW = W + (size_t)(n0 + srow) * K + skc;
  const int lo = wave * 32 * 32;   // wave's slice offset within a buffer

  const int niter = K >> 5;
  // prologue: stage tiles 0 and 1
  gl2lds16(gA, &As[0][lo]);
  gl2lds16(gA + (size_t)16 * K, &As[0][lo + 16 * 32]);
  gl2lds16(gW, &Ws[0][lo]);
  gl2lds16(gW + (size_t)16 * K, &Ws[0][lo + 16 * 32]);
  if (niter > 1) {
    gl2lds16(gA + 32, &As[1][lo]);
    gl2lds16(gA + (size_t)16 * K + 32, &As[1][lo + 16 * 32]);
    gl2lds16(gW + 32, &Ws[1][lo]);
    gl2lds16(gW + (size_t)16 * K + 32, &Ws[1][lo + 16 * 32]);
  }

  // reader chunk position for this lane (row-mod-16 invariant)
  const int prd = ((quad - (l16 >> 1)) & 3) * 8;

  for (int it = 0; it < niter; ++it) {
    // wait for tile `it` only (4 of our loads); keep tile it+1 in flight.
    if (it + 1 < niter)
      asm volatile("s_waitcnt vmcnt(4)\n\ts_barrier" ::: "memory");
    else
      asm volatile("s_waitcnt vmcnt(0)\n\ts_barrier" ::: "memory");
    // prefetch tile it+2 into the buffer last read at iter it-1 (all waves
    // finished those reads before this barrier).
    if (it + 2 < niter) {
      const int kpre = (it + 2) * 32;
      const int nb = (it + 2) % 3;
      gl2lds16(gA + kpre, &As[nb][lo]);
      gl2lds16(gA + (size_t)16 * K + kpre, &As[nb][lo + 16 * 32]);
      gl2lds16(gW + kpre, &Ws[nb][lo]);
      gl2lds16(gW + (size_t)16 * K + kpre, &Ws[nb][lo + 16 * 32]);
    }
    const int cb = it % 3;
    short8 af[4], bf[4];
#pragma unroll
    for (int t = 0; t < 4; t++) {
      af[t] = *(const short8*)&As[cb][(mw + t * 16 + l16) * 32 + prd];
      bf[t] = *(const short8*)&Ws[cb][(nw + t * 16 + l16) * 32 + prd];
    }
#pragma unroll
    for (int mt = 0; mt < 4; mt++)
#pragma unroll
      for (int nt = 0; nt < 4; nt++)
        acc[mt][nt] = __builtin_amdgcn_mfma_f32_16x16x32_bf16(
            af[mt], bf[nt], acc[mt][nt], 0, 0, 0);
  }

  // ---- vectorized epilogue (fp32 LDS transpose, 2 passes of 32 rows) ----
  __syncthreads();  // all waves done with K-loop LDS reads
  float* eps = ((wave < 2) ? (float*)As : (float*)Ws) + (wave & 1) * (32 * 68);
  const int erow = lane >> 3;        // 0..7
  const int ec = (lane & 7) * 8;     // output col chunk base
#pragma unroll
  for (int pass = 0; pass < 2; pass++) {
#pragma unroll
    for (int mh = 0; mh < 2; mh++) {
      const int mt = pass * 2 + mh;
#pragma unroll
      for (int nt = 0; nt < 4; nt++) {
        const float bv = bias[n0 + nw + nt * 16 + l16];
#pragma unroll
        for (int i = 0; i < 4; i++)
          eps[(mh * 16 + quad * 4 + i) * 68 + nt * 16 + l16] =
              acc[mt][nt][i] + bv;
      }
    }
    asm volatile("s_waitcnt lgkmcnt(0)" ::: "memory");
#pragma unroll
    for (int j = 0; j < 4; j++) {
      const int r = j * 8 + erow;                  // 0..31
      const int m = m0 + mw + pass * 32 + r;
      const int n = n0 + nw + ec;
      f32x4 v0 = *(const f32x4*)&eps[r * 68 + ec];
      f32x4 v1 = *(const f32x4*)&eps[r * 68 + ec + 4];
      float v[8] = {v0[0], v0[1], v0[2], v0[3], v1[0], v1[1], v1[2], v1[3]};
      if (res) {
        ushort8 rv = *(const ushort8*)((const unsigned short*)res +
                                       (size_t)m * N + n);
#pragma unroll
        for (int t = 0; t < 8; t++) v[t] += b2f(rv[t]);
      }
      ushort8 o;
#pragma unroll
      for (int t = 0; t < 8; t++) {
        float x = (act == 1) ? fmaxf(v[t], 0.0f) : v[t];
        o[t] = f2b(x);
      }
      *(ushort8*)((unsigned short*)C + (size_t)m * N + n) = o;
    }
    // reads of this pass complete before next pass overwrites the region
    asm volatile("s_waitcnt lgkmcnt(0)" ::: "memory");
  }
}

// ---------------------------------------------------------------------------
// fp32 SIMT GEMM (kept for the tiny head): 64x64 tile.
__global__ __launch_bounds__(256) void gemm_k(
    const float* __restrict__ A, const float* __restrict__ W,
    const float* __restrict__ bias, const float* __restrict__ res,
    float* __restrict__ C, int M, int N, int K, int act) {
  __shared__ float As[16][68];
  __shared__ float Ws[16][68];
  const int tid = threadIdx.x;
  const int tx = tid & 15, ty = tid >> 4;
  const int m0 = blockIdx.y * 64, n0 = blockIdx.x * 64;
  const int lr = tid >> 2;
  const int lk = (tid & 3) * 4;
  float acc[4][4] = {{0.f}};
  for (int k0 = 0; k0 < K; k0 += 16) {
#pragma unroll
    for (int i = 0; i < 4; i++) {
      int k = k0 + lk + i;
      As[lk + i][lr] = (k < K) ? A[(size_t)(m0 + lr) * K + k] : 0.0f;
      Ws[lk + i][lr] = (k < K) ? W[(size_t)(n0 + lr) * K + k] : 0.0f;
    }
    __syncthreads();
#pragma unroll
    for (int kk = 0; kk < 16; kk++) {
      float4 a4 = *(const float4*)&As[kk][ty * 4];
      float4 w4 = *(const float4*)&Ws[kk][tx * 4];
      float a[4] = {a4.x, a4.y, a4.z, a4.w};
      float w[4] = {w4.x, w4.y, w4.z, w4.w};
#pragma unroll
      for (int i = 0; i < 4; i++)
#pragma unroll
        for (int j = 0; j < 4; j++) acc[i][j] += a[i] * w[j];
    }
    __syncthreads();
  }
#pragma unroll
  for (int i = 0; i < 4; i++) {
    int m = m0 + ty * 4 + i;
#pragma unroll
    for (int j = 0; j < 4; j++) {
      int n = n0 + tx * 4 + j;
      float v = acc[i][j] + bias[n];
      if (res) v += res[(size_t)m * N + n];
      if (act == 1) v = fmaxf(v, 0.0f);
      else if (act == 2) v = v / (1.0f + __expf(-v));
      C[(size_t)m * N + n] = v;
    }
  }
}

// ---------------------------------------------------------------------------
// Row LayerNorm over D=512, bf16 in/out, fp32 params. 4 rows/block.
__global__ __launch_bounds__(256) void lnb_k(
    const __hip_bfloat16* __restrict__ in, const float* __restrict__ g,
    const float* __restrict__ b, __hip_bfloat16* __restrict__ out) {
  int row = blockIdx.x * 4 + (threadIdx.x >> 6);
  int lane = threadIdx.x & 63;
  const unsigned short* rp =
      (const unsigned short*)in + (size_t)row * DMODEL + lane * 8;
  ushort8 sv = *(const ushort8*)rp;
  float v[8];
  float s = 0.f;
#pragma unroll
  for (int i = 0; i < 8; i++) { v[i] = b2f(sv[i]); s += v[i]; }
#pragma unroll
  for (int off = 32; off; off >>= 1) s += __shfl_xor(s, off);
  float mu = s * (1.0f / DMODEL);
  float vs = 0.f;
#pragma unroll
  for (int i = 0; i < 8; i++) { float d = v[i] - mu; vs += d * d; }
#pragma unroll
  for (int off = 32; off; off >>= 1) vs += __shfl_xor(vs, off);
  float rs = rsqrtf(vs * (1.0f / DMODEL) + 1e-5f);
  ushort8 o;
#pragma unroll
  for (int i = 0; i < 8; i++) {
    int c = lane * 8 + i;
    o[i] = f2b((v[i] - mu) * rs * g[c] + b[c]);
  }
  *(ushort8*)((unsigned short*)out + (size_t)row * DMODEL + lane * 8) = o;
}

// ---------------------------------------------------------------------------
// MFMA ragged attention, key-split flash halves.
// Block = (graph, head, key-half); 4 waves. Each half computes, for EVERY
// query q of the graph: O'[q] = sum_{k in half} e^{s_qk - m_half} V_k (bf16,
// unnormalized) plus (m_half, l_half) into ml[]. merge_k renormalizes.
// LDS: Ks[128][72] + Vt[64][136] + Ps[4][16][136] = 52 KB -> 3 blocks/CU.
// Ps ordering fence is lgkmcnt-only (wave-local LDS W->R).
#define MAXNH 128
__global__ __launch_bounds__(256, 3) void attn5_k(
    const __hip_bfloat16* __restrict__ qkv, const int* __restrict__ starts,
    __hip_bfloat16* __restrict__ O1, __hip_bfloat16* __restrict__ O2,
    float* __restrict__ ml) {
  const int half = blockIdx.x & 1;
  const int gh = blockIdx.x >> 1;
  const int g = gh >> 3, h = gh & 7;
  int s0 = starts[g], s1 = starts[g + 1];
  s0 = min(max(s0, 0), N_NODES);
  s1 = min(max(s1, s0), N_NODES);
  const int n = s1 - s0, start = s0;
  if (n == 0) return;
  const int tid = threadIdx.x, wave = tid >> 6, lane = tid & 63;
  const int quad = lane >> 4, l16 = lane & 15;
  unsigned short* Oh = (unsigned short*)(half ? O2 : O1);

  __shared__ __align__(16) unsigned short Ks[128][72];     // K rows [key][d]
  __shared__ __align__(16) unsigned short Vt[64][136];     // V^T [d][key]
  __shared__ __align__(16) unsigned short Ps[4][16][136];  // per-wave P[q][key]

  if (n <= 2 * MAXNH) {
    const int nh1 = (n + 1) >> 1;
    const int k0g = half * nh1;                 // this half's first key
    const int nh = half ? (n - nh1) : nh1;      // this half's key count
    const int ktq = (n + 15) >> 4;              // query tiles (full n)

    if (nh == 0) {  // empty half (n==1): emit zero partials for all queries
      for (int mt = wave; mt < ktq; mt += 4) {
        const int q = mt * 16 + l16;
        if (q < n) {
          short4v z = {0, 0, 0, 0};
#pragma unroll
          for (int dt = 0; dt < 4; dt++)
            *(short4v*)(Oh + (size_t)(start + q) * DMODEL + h * HDIM +
                        dt * 16 + quad * 4) = z;
          if (quad == 0) {
            float2 mlv = {-FLT_MAX, 0.0f};
            *(float2*)(ml + ((size_t)(start + q) * NHEAD + h) * 4 + half * 2) = mlv;
          }
        }
      }
      return;
    }

    // ---- stage K rows of this half ----
    for (int idx = tid; idx < nh * 8; idx += 256) {
      int r = idx >> 3, c = (idx & 7) * 8;
      *(ushort8*)&Ks[r][c] = *(const ushort8*)((const unsigned short*)qkv +
                                               (size_t)(start + k0g + r) * 1536 +
                                               512 + h * HDIM + c);
    }
    // zero K pad rows [nh, min(128, nh+16))
    for (int idx = tid; idx < 16 * 8; idx += 256) {
      int r = nh + (idx >> 3), c = (idx & 7) * 8;
      if (r < 128) {
        ushort8 z = {0, 0, 0, 0, 0, 0, 0, 0};
        *(ushort8*)&Ks[r][c] = z;
      }
    }
    // ---- stage V transposed: Vt[d][r] = V[k0g+r][d] ----
    const int vr = tid & 31, dc8 = tid >> 5;
    for (int r0 = 0; r0 < nh; r0 += 32) {
      int r = r0 + vr;
      if (r < nh) {
        ushort8 v = *(const ushort8*)((const unsigned short*)qkv +
                                      (size_t)(start + k0g + r) * 1536 + 1024 +
                                      h * HDIM + dc8 * 8);
#pragma unroll
        for (int j = 0; j < 8; j++) Vt[dc8 * 8 + j][r] = v[j];
      }
    }
    // zero key cols [nh, nh+32)
    for (int idx = tid; idx < 64 * 32; idx += 256) {
      int d = idx >> 5, r = nh + (idx & 31);
      if (r < 136) Vt[d][r] = 0;
    }
    __syncthreads();

    const int ktmax2 = (nh + 15) >> 4;  // key tiles in this half (<=8)
    const int nkc2 = (nh + 31) >> 5;    // 32-wide key chunks (<=4)
    const float scale = 0.125f;

    for (int mt = wave; mt < ktq; mt += 4) {
      // Q fragments: lane l16 = q, dims quad*8..+7 per 32-chunk
      const int qrow = start + min(mt * 16 + l16, n - 1);
      const short8 qf0 = *(const short8*)((const unsigned short*)qkv +
                                          (size_t)qrow * 1536 + h * HDIM + quad * 8);
      const short8 qf1 = *(const short8*)((const unsigned short*)qkv +
                                          (size_t)qrow * 1536 + h * HDIM + 32 + quad * 8);
      f32x4 sacc[8];
      // ---- scores: S^T[key][q] = K . Q^T (K-frags from LDS) ----
#pragma unroll
      for (int kt = 0; kt < 8; kt++) {
        if (kt < ktmax2) {
          const int krow = kt * 16 + l16;
          const short8 kf0 = *(const short8*)&Ks[krow][quad * 8];
          const short8 kf1 = *(const short8*)&Ks[krow][32 + quad * 8];
          f32x4 a = {0.f, 0.f, 0.f, 0.f};
          a = __builtin_amdgcn_mfma_f32_16x16x32_bf16(kf0, qf0, a, 0, 0, 0);
          a = __builtin_amdgcn_mfma_f32_16x16x32_bf16(kf1, qf1, a, 0, 0, 0);
          sacc[kt] = a;
        }
      }
      // ---- local softmax stats for q = l16 over this half's keys ----
      float mx = -FLT_MAX;
#pragma unroll
      for (int kt = 0; kt < 8; kt++) {
        if (kt < ktmax2) {
#pragma unroll
          for (int i = 0; i < 4; i++) {
            const int key = kt * 16 + quad * 4 + i;
            const float v = sacc[kt][i] * scale;
            sacc[kt][i] = v;
            if (key < nh) mx = fmaxf(mx, v);
          }
        }
      }
      mx = fmaxf(mx, __shfl_xor(mx, 16));
      mx = fmaxf(mx, __shfl_xor(mx, 32));
      float ls = 0.f;
#pragma unroll
      for (int kt = 0; kt < 8; kt++) {
        if (kt < ktmax2) {
#pragma unroll
          for (int i = 0; i < 4; i++) {
            const int key = kt * 16 + quad * 4 + i;
            const float p = (key < nh) ? __expf(sacc[kt][i] - mx) : 0.0f;
            sacc[kt][i] = p;
            ls += p;
          }
        }
      }
      ls += __shfl_xor(ls, 16);
      ls += __shfl_xor(ls, 32);
      // ---- store UNNORMALIZED p (bf16) to Ps; zero kt in [ktmax2, 2*nkc2) ----
#pragma unroll
      for (int kt = 0; kt < 8; kt++) {
        if (kt < 2 * nkc2) {
          short4v pp;
#pragma unroll
          for (int i = 0; i < 4; i++) {
            const float p = (kt < ktmax2) ? sacc[kt][i] : 0.0f;
            pp[i] = (short)f2b(p);
          }
          *(short4v*)&Ps[wave][l16][kt * 16 + quad * 4] = pp;
        }
      }
      // wave-local LDS write->read ordering: lgkm-only (no vmcnt drain)
      asm volatile("s_waitcnt lgkmcnt(0)" ::: "memory");
      // ---- PV: O'[d][q] = sum_key V^T[d][key] * p[q][key] ----
      const int qv = mt * 16 + l16;
#pragma unroll
      for (int dt = 0; dt < 4; dt++) {
        f32x4 oa = {0.f, 0.f, 0.f, 0.f};
#pragma unroll
        for (int kc = 0; kc < 4; kc++) {
          if (kc < nkc2) {
            const short8 vf = *(const short8*)&Vt[dt * 16 + l16][kc * 32 + quad * 8];
            const short8 pf = *(const short8*)&Ps[wave][l16][kc * 32 + quad * 8];
            oa = __builtin_amdgcn_mfma_f32_16x16x32_bf16(vf, pf, oa, 0, 0, 0);
          }
        }
        if (qv < n) {
          short4v ov;
#pragma unroll
          for (int i = 0; i < 4; i++) ov[i] = (short)f2b(oa[i]);
          *(short4v*)(Oh + (size_t)(start + qv) * DMODEL + h * HDIM +
                      dt * 16 + quad * 4) = ov;
        }
      }
      if (qv < n && quad == 0) {
        float2 mlv = {mx, ls};
        *(float2*)(ml + ((size_t)(start + qv) * NHEAD + h) * 4 + half * 2) = mlv;
      }
    }
  } else {
    // fallback (n in (256,512]; statistically never). half 0 computes the
    // full normalized attention -> O1, ml=(0,1); half 1 emits zero partials.
    const float scale = 0.125f;
    int nn = min(n, 512);
    if (half == 1) {
      for (int qi = wave; qi < nn; qi += 4) {
        Oh[(size_t)(start + qi) * DMODEL + h * HDIM + lane] = 0;
        if (lane == 0) {
          float2 mlv = {-FLT_MAX, 0.0f};
          *(float2*)(ml + ((size_t)(start + qi) * NHEAD + h) * 4 + 2) = mlv;
        }
      }
      return;
    }
    for (int qi = wave; qi < nn; qi += 4) {
      float qd = __bfloat162float(
          qkv[(size_t)(start + qi) * (3 * DMODEL) + h * HDIM + lane]);
      float sreg[8];
#pragma unroll
      for (int t = 0; t < 8; t++) {
        float sc = -FLT_MAX;
        if (t * 64 < nn) {
          int k = t * 64 + lane, kc = min(k, nn - 1);
          const __hip_bfloat16* Kr =
              qkv + (size_t)(start + kc) * (3 * DMODEL) + DMODEL + h * HDIM;
          float a = 0.f;
#pragma unroll
          for (int d = 0; d < 64; d++)
            a += __shfl(qd, d) * __bfloat162float(Kr[d]);
          if (k < nn) sc = a * scale;
        }
        sreg[t] = sc;
      }
      float m = -FLT_MAX;
#pragma unroll
      for (int t = 0; t < 8; t++) m = fmaxf(m, sreg[t]);
#pragma unroll
      for (int off = 32; off; off >>= 1) m = fmaxf(m, __shfl_xor(m, off));
      float lsum = 0.f;
#pragma unroll
      for (int t = 0; t < 8; t++) {
        float p = (sreg[t] == -FLT_MAX) ? 0.0f : __expf(sreg[t] - m);
        sreg[t] = p;
        lsum += p;
      }
#pragma unroll
      for (int off = 32; off; off >>= 1) lsum += __shfl_xor(lsum, off);
      float inv_l = 1.0f / lsum;
      float o = 0.f;
#pragma unroll
      for (int t = 0; t < 8; t++) {
        int kb = t * 64;
        if (kb < nn) {
          int kmax = min(64, nn - kb);
          const __hip_bfloat16* Vb = qkv + (size_t)(start + kb) * (3 * DMODEL) +
                                     2 * DMODEL + h * HDIM + lane;
          for (int j = 0; j < kmax; j++)
            o += __shfl(sreg[t], j) *
                 __bfloat162float(Vb[(size_t)j * (3 * DMODEL)]);
        }
      }
      Oh[(size_t)(start + qi) * DMODEL + h * HDIM + lane] = f2b(o * inv_l);
      if (lane == 0) {
        float2 mlv = {0.0f, 1.0f};
        *(float2*)(ml + ((size_t)(start + qi) * NHEAD + h) * 4) = mlv;
      }
    }
  }
}

// ---------------------------------------------------------------------------
// Merge the two key-half partials: out = (w1*O1 + w2*O2)/(w1*l1 + w2*l2),
// w_c = e^{m_c - max(m1,m2)}. One thread per (node, head, 8 dims).
__global__ __launch_bounds__(256) void merge_k(
    const __hip_bfloat16* __restrict__ O1, const __hip_bfloat16* __restrict__ O2,
    const float* __restrict__ ml, __hip_bfloat16* __restrict__ out) {
  int t = blockIdx.x * 256 + threadIdx.x;     // t < N_NODES*64
  int node = t >> 6;
  int rem = t & 63;
  int h = rem >> 3;
  int c8 = (rem & 7) * 8;
  float4 m4 = *(const float4*)(ml + ((size_t)node * NHEAD + h) * 4);
  float mm = fmaxf(m4.x, m4.z);
  float w1 = __expf(m4.x - mm), w2 = __expf(m4.z - mm);
  float inv = 1.0f / (w1 * m4.y + w2 * m4.w);
  size_t off = (size_t)node * DMODEL + h * HDIM + c8;
  ushort8 a = *(const ushort8*)((const unsigned short*)O1 + off);
  ushort8 b = *(const ushort8*)((const unsigned short*)O2 + off);
  ushort8 o;
#pragma unroll
  for (int i = 0; i < 8; i++)
    o[i] = f2b((w1 * b2f(a[i]) + w2 * b2f(b[i])) * inv);
  *(ushort8*)((unsigned short*)out + off) = o;
}

// ---------------------------------------------------------------------------
// Segment-mean pool, bf16 in, fp32 out. Grid (graphs, 2 col-chunks).
__global__ __launch_bounds__(256) void pool_k(
    const __hip_bfloat16* __restrict__ hp, const int* __restrict__ starts,
    float* __restrict__ pooled) {
  int g = blockIdx.x;
  int s0 = starts[g], s1 = starts[g + 1];
  s0 = min(max(s0, 0), N_NODES);
  s1 = min(max(s1, s0), N_NODES);
  int n = s1 - s0;
  float inv = n > 0 ? 1.0f / (float)n : 0.0f;
  int c = blockIdx.y * 256 + threadIdx.x;
  float acc = 0.f;
  for (int r = s0; r < s1; r++)
    acc += __bfloat162float(hp[(size_t)r * DMODEL + c]);
  pooled[(size_t)g * DMODEL + c] = acc * inv;
}

// ---------------------------------------------------------------------------
__global__ __launch_bounds__(256) void head2_k(
    const float* __restrict__ h1, const float* __restrict__ w2,
    const float* __restrict__ b2, float* __restrict__ y) {
  int row = blockIdx.x * 4 + (threadIdx.x >> 6);
  int lane = threadIdx.x & 63;
  float s = 0.f;
#pragma unroll
  for (int i = 0; i < 8; i++) {
    int c = lane + i * 64;
    s += h1[(size_t)row * DMODEL + c] * w2[c];
  }
#pragma unroll
  for (int off = 32; off; off >>= 1) s += __shfl_xor(s, off);
  if (lane == 0) y[row] = s + b2[0];
}

// ---------------------------------------------------------------------------
extern "C" void kernel_launch(void* const* d_in, const int* in_sizes, int n_in,
                              void* d_out, int out_size, void* d_ws,
                              size_t ws_size, hipStream_t stream) {
  const float* node_features = (const float*)d_in[0];
  const int* batch = (const int*)d_in[3];
  const float* emb_w = (const float*)d_in[4];
  const float* emb_b = (const float*)d_in[5];
  const float* in_proj_w = (const float*)d_in[6];
  const float* in_proj_b = (const float*)d_in[7];
  const float* out_w = (const float*)d_in[8];
  const float* out_b = (const float*)d_in[9];
  const float* ln1_g = (const float*)d_in[10];
  const float* ln1_b = (const float*)d_in[11];
  const float* ffn_w1 = (const float*)d_in[12];
  const float* ffn_b1 = (const float*)d_in[13];
  const float* ffn_w2 = (const float*)d_in[14];
  const float* ffn_b2 = (const float*)d_in[15];
  const float* ln2_g = (const float*)d_in[16];
  const float* ln2_b = (const float*)d_in[17];
  const float* head_w1 = (const float*)d_in[18];
  const float* head_b1 = (const float*)d_in[19];
  const float* head_w2 = (const float*)d_in[20];
  const float* head_b2 = (const float*)d_in[21];
  float* y = (float*)d_out;

  typedef __hip_bfloat16 bf;
  char* wsb = (char*)d_ws;
  int* starts = (int*)wsb;
  bf* nf_b = (bf*)(wsb + 1024);                        // N x 96
  bf* wq_b = nf_b + (size_t)N_NODES * D_INP;           // L x 1536 x 512
  bf* wo_b = wq_b + (size_t)NLAYER * 3 * DMODEL * DMODEL;
  bf* w1_b = wo_b + (size_t)NLAYER * DMODEL * DMODEL;
  bf* w2_b = w1_b + (size_t)NLAYER * DFF * DMODEL;
  bf* we_b = w2_b + (size_t)NLAYER * DMODEL * DFF;     // 512 x 96
  bf* hp   = we_b + (size_t)DMODEL * D_INP;            // N x 512
  bf* xb   = hp + (size_t)N_NODES * DMODEL;            // N x 512 (O2 half)
  bf* t1b  = xb + (size_t)N_NODES * DMODEL;            // N x 512 (O1 half / attn out)
  bf* qkvb = t1b + (size_t)N_NODES * DMODEL;           // N x 1536
  bf* ffh  = qkvb;                                     // N x 2048 (overlays qkv, +25MB)
  float* pooled = (float*)((char*)ffh + (size_t)N_NODES * DFF * 2);
  float* h1 = pooled + (size_t)B_GRAPHS * DMODEL;
  float* ml = h1 + (size_t)B_GRAPHS * DMODEL;          // N x 8 x 4 floats

  starts_k<<<1, 256, 0, stream>>>(batch, starts);

  {
    int c4;
    c4 = NLAYER * 3 * DMODEL * DMODEL / 4;
    cvt_k<<<(c4 + 255) / 256, 256, 0, stream>>>(in_proj_w, wq_b, c4);
    c4 = NLAYER * DMODEL * DMODEL / 4;
    cvt_k<<<(c4 + 255) / 256, 256, 0, stream>>>(out_w, wo_b, c4);
    c4 = NLAYER * DFF * DMODEL / 4;
    cvt_k<<<(c4 + 255) / 256, 256, 0, stream>>>(ffn_w1, w1_b, c4);
    cvt_k<<<(c4 + 255) / 256, 256, 0, stream>>>(ffn_w2, w2_b, c4);
    padcvt_k<<<(N_NODES * D_INP + 255) / 256, 256, 0, stream>>>(node_features,
                                                                nf_b, N_NODES);
    padcvt_k<<<(DMODEL * D_INP + 255) / 256, 256, 0, stream>>>(emb_w, we_b,
                                                               DMODEL);
  }

  // embed: hp = nf @ emb_w^T + emb_b  (K=96)
  mgemm_k<<<(N_NODES / 128) * (DMODEL / 128), 256, 0, stream>>>(
      nf_b, we_b, emb_b, nullptr, hp, N_NODES, DMODEL, D_INP, 0);

  for (int l = 0; l < NLAYER; l++) {
    const bf* wq = wq_b + (size_t)l * 3 * DMODEL * DMODEL;
    const bf* wo = wo_b + (size_t)l * DMODEL * DMODEL;
    const bf* w1 = w1_b + (size_t)l * DFF * DMODEL;
    const bf* w2 = w2_b + (size_t)l * DMODEL * DFF;
    const float* ipb = in_proj_b + (size_t)l * 3 * DMODEL;
    const float* ob = out_b + (size_t)l * DMODEL;
    const float* b1 = ffn_b1 + (size_t)l * DFF;
    const float* b2 = ffn_b2 + (size_t)l * DMODEL;

    // qkv = hp @ in_proj^T + b
    mgemm_k<<<(N_NODES / 128) * (3 * DMODEL / 128), 256, 0, stream>>>(
        hp, wq, ipb, nullptr, qkvb, N_NODES, 3 * DMODEL, DMODEL, 0);

    // attention halves -> t1b (half0) / xb (half1), then merge -> t1b
    attn5_k<<<B_GRAPHS * NHEAD * 2, 256, 0, stream>>>(qkvb, starts, t1b, xb, ml);
    merge_k<<<N_NODES * 64 / 256, 256, 0, stream>>>(t1b, xb, ml, t1b);

    // xb = t1b @ out_w^T + out_b + hp ; then LN in-place
    mgemm_k<<<(N_NODES / 128) * (DMODEL / 128), 256, 0, stream>>>(
        t1b, wo, ob, hp, xb, N_NODES, DMODEL, DMODEL, 0);
    lnb_k<<<N_NODES / 4, 256, 0, stream>>>(xb, ln1_g + l * DMODEL,
                                           ln1_b + l * DMODEL, xb);

    // FFN, single dispatch each (ffh overlays the dead qkv region)
    mgemm_k<<<(N_NODES / 128) * (DFF / 128), 256, 0, stream>>>(
        xb, w1, b1, nullptr, ffh, N_NODES, DFF, DMODEL, 1);
    mgemm_k<<<(N_NODES / 128) * (DMODEL / 128), 256, 0, stream>>>(
        ffh, w2, b2, xb, t1b, N_NODES, DMODEL, DFF, 0);

    lnb_k<<<N_NODES / 4, 256, 0, stream>>>(t1b, ln2_g + l * DMODEL,
                                           ln2_b + l * DMODEL, hp);
  }

  pool_k<<<dim3(B_GRAPHS, 2), 256, 0, stream>>>(hp, starts, pooled);
  gemm_k<<<dim3(DMODEL / 64, B_GRAPHS / 64), 256, 0, stream>>>(
      pooled, head_w1, head_b1, nullptr, h1, B_GRAPHS, DMODEL, DMODEL, 2);
  head2_k<<<B_GRAPHS / 4, 256, 0, stream>>>(h1, head_w2, head_b2, y);
}

// Round 13
// 1157.341 us; speedup vs baseline: 1.4947x; 1.0079x over previous
//
#include <hip/hip_runtime.h>
#include <hip/hip_bf16.h>
#include <cstdint>
#include <cfloat>
#include <cstddef>
#include <type_traits>

#define N_NODES 24576
#define B_GRAPHS 128
#define D_IN 92
#define D_INP 96           // D_IN padded to multiple of 32 for MFMA K
#define DMODEL 512
#define NHEAD 8
#define HDIM 64
#define NLAYER 3
#define DFF 2048

typedef __attribute__((ext_vector_type(8))) short short8;
typedef __attribute__((ext_vector_type(4))) short short4v;
typedef __attribute__((ext_vector_type(8))) unsigned short ushort8;
typedef __attribute__((ext_vector_type(4))) float f32x4;

__device__ __forceinline__ float b2f(unsigned short u) {
  union { unsigned int i; float f; } x;
  x.i = ((unsigned int)u) << 16;
  return x.f;
}
__device__ __forceinline__ unsigned short f2b(float f) {
  __hip_bfloat16 h = __float2bfloat16(f);
  return *reinterpret_cast<unsigned short*>(&h);
}

// async global->LDS, 16B per lane; LDS dest = wave-uniform base + lane*16
__device__ __forceinline__ void gl2lds16(const __hip_bfloat16* g,
                                         __hip_bfloat16* l) {
  __builtin_amdgcn_global_load_lds(
      (const __attribute__((address_space(1))) unsigned int*)g,
      (__attribute__((address_space(3))) unsigned int*)l, 16, 0, 0);
}

// ---------------------------------------------------------------------------
// starts[g] = lower_bound(batch, g); handles int32 or int64 batch (sniffed).
__global__ void starts_k(const int* __restrict__ batch32, int* __restrict__ starts) {
  __shared__ int is64_s;
  const int tid = threadIdx.x;
  if (tid == 0) is64_s = 0;
  __syncthreads();
  int bad = 0;
  for (int i = tid; i < N_NODES - 1; i += 256)
    if (batch32[i] > batch32[i + 1]) bad = 1;
  if (bad) atomicOr(&is64_s, 1);
  __syncthreads();
  const int is64 = is64_s;
  if (tid <= B_GRAPHS) {
    int lo = 0, hi = N_NODES;
    while (lo < hi) {
      int mid = (lo + hi) >> 1;
      int v = is64 ? batch32[2 * mid] : batch32[mid];
      if (v < tid) lo = mid + 1; else hi = mid;
    }
    starts[tid] = lo;
  }
}

// ---------------------------------------------------------------------------
// One-dispatch prep: converts all 4 weight groups fp32->bf16 (flat quads) and
// the two 92->96 padded conversions (nf, emb_w). Region-branched by quad idx.
#define QW0 589824   // in_proj_w quads (3*1536*512/4)
#define QW1 196608   // out_w quads
#define QW2 786432   // ffn_w1 quads
#define QW3 786432   // ffn_w2 quads
#define QP4 589824   // node_features padded quads (24576*96/4)
#define QP5 12288    // emb_w padded quads (512*96/4)
#define QTOT (QW0 + QW1 + QW2 + QW3 + QP4 + QP5)
__global__ __launch_bounds__(256) void prep_k(
    const float* __restrict__ s0, const float* __restrict__ s1,
    const float* __restrict__ s2, const float* __restrict__ s3,
    const float* __restrict__ s4, const float* __restrict__ s5,
    __hip_bfloat16* __restrict__ d0, __hip_bfloat16* __restrict__ d1,
    __hip_bfloat16* __restrict__ d2, __hip_bfloat16* __restrict__ d3,
    __hip_bfloat16* __restrict__ d4, __hip_bfloat16* __restrict__ d5) {
  int q = blockIdx.x * 256 + threadIdx.x;
  const float* src;
  __hip_bfloat16* dst;
  int qi;
  bool pad = false;
  if (q < QW0) { src = s0; dst = d0; qi = q; }
  else if ((q -= QW0) < QW1) { src = s1; dst = d1; qi = q; }
  else if ((q -= QW1) < QW2) { src = s2; dst = d2; qi = q; }
  else if ((q -= QW2) < QW3) { src = s3; dst = d3; qi = q; }
  else if ((q -= QW3) < QP4) { src = s4; dst = d4; qi = q; pad = true; }
  else if ((q -= QP4) < QP5) { src = s5; dst = d5; qi = q; pad = true; }
  else return;
  float4 v;
  if (!pad) {
    v = ((const float4*)src)[qi];
  } else {
    // dest row-major (rows x 96); quad 23 of each row (cols 92..95) is zero.
    int r = qi / 24, cq = (qi % 24) * 4;
    if (cq < 92) {
      const float* p = src + (size_t)r * D_IN + cq;
      v = make_float4(p[0], p[1], p[2], p[3]);
    } else {
      v = make_float4(0.f, 0.f, 0.f, 0.f);
    }
  }
  short4v o;
  o[0] = (short)f2b(v.x); o[1] = (short)f2b(v.y);
  o[2] = (short)f2b(v.z); o[3] = (short)f2b(v.w);
  ((short4v*)dst)[qi] = o;
}

// ---------------------------------------------------------------------------
// bf16 MFMA GEMM (r9 K-loop + r12 vectorized epilogue). See r12 notes.
__global__ __launch_bounds__(256) void mgemm_k(
    const __hip_bfloat16* __restrict__ A, const __hip_bfloat16* __restrict__ W,
    const float* __restrict__ bias, const __hip_bfloat16* __restrict__ res,
    __hip_bfloat16* __restrict__ C, int M, int N, int K, int act) {
  __shared__ __align__(16) __hip_bfloat16 As[3][128 * 32];
  __shared__ __align__(16) __hip_bfloat16 Ws[3][128 * 32];
  const int tid = threadIdx.x;
  const int wave = tid >> 6, lane = tid & 63;

  const int nxt = N >> 7, nmt = M >> 7;
  int rowt, colt;
  if ((nmt & 7) == 0) {
    const int rows_per = nmt >> 3;      // row tiles per XCD stripe
    const int x = blockIdx.x & 7;       // XCD (dispatch round-robin)
    const int j = blockIdx.x >> 3;
    rowt = x * rows_per + j % rows_per; // col-major within stripe
    colt = j / rows_per;
  } else {
    rowt = blockIdx.x / nxt;
    colt = blockIdx.x % nxt;
  }
  const int m0 = rowt * 128, n0 = colt * 128;

  const int mw = (wave >> 1) * 64, nw = (wave & 1) * 64;
  const int quad = lane >> 4, l16 = lane & 15;

  f32x4 acc[4][4] = {};

  const int srow = wave * 32 + (lane >> 2);
  const int skc = (((lane & 3) + ((lane >> 2) >> 1)) & 3) * 8;
  const __hip_bfloat16* gA = A + (size_t)(m0 + srow) * K + skc;
  const __hip_bfloat16* gW = W + (size_t)(n0 + srow) * K + skc;
  const int lo = wave * 32 * 32;

  const int niter = K >> 5;
  gl2lds16(gA, &As[0][lo]);
  gl2lds16(gA + (size_t)16 * K, &As[0][lo + 16 * 32]);
  gl2lds16(gW, &Ws[0][lo]);
  gl2lds16(gW + (size_t)16 * K, &Ws[0][lo + 16 * 32]);
  if (niter > 1) {
    gl2lds16(gA + 32, &As[1][lo]);
    gl2lds16(gA + (size_t)16 * K + 32, &As[1][lo + 16 * 32]);
    gl2lds16(gW + 32, &Ws[1][lo]);
    gl2lds16(gW + (size_t)16 * K + 32, &Ws[1][lo + 16 * 32]);
  }

  const int prd = ((quad - (l16 >> 1)) & 3) * 8;

  for (int it = 0; it < niter; ++it) {
    if (it + 1 < niter)
      asm volatile("s_waitcnt vmcnt(4)\n\ts_barrier" ::: "memory");
    else
      asm volatile("s_waitcnt vmcnt(0)\n\ts_barrier" ::: "memory");
    if (it + 2 < niter) {
      const int kpre = (it + 2) * 32;
      const int nb = (it + 2) % 3;
      gl2lds16(gA + kpre, &As[nb][lo]);
      gl2lds16(gA + (size_t)16 * K + kpre, &As[nb][lo + 16 * 32]);
      gl2lds16(gW + kpre, &Ws[nb][lo]);
      gl2lds16(gW + (size_t)16 * K + kpre, &Ws[nb][lo + 16 * 32]);
    }
    const int cb = it % 3;
    short8 af[4], bf[4];
#pragma unroll
    for (int t = 0; t < 4; t++) {
      af[t] = *(const short8*)&As[cb][(mw + t * 16 + l16) * 32 + prd];
      bf[t] = *(const short8*)&Ws[cb][(nw + t * 16 + l16) * 32 + prd];
    }
#pragma unroll
    for (int mt = 0; mt < 4; mt++)
#pragma unroll
      for (int nt = 0; nt < 4; nt++)
        acc[mt][nt] = __builtin_amdgcn_mfma_f32_16x16x32_bf16(
            af[mt], bf[nt], acc[mt][nt], 0, 0, 0);
  }

  // ---- vectorized epilogue (fp32 LDS transpose, 2 passes of 32 rows) ----
  __syncthreads();
  float* eps = ((wave < 2) ? (float*)As : (float*)Ws) + (wave & 1) * (32 * 68);
  const int erow = lane >> 3;
  const int ec = (lane & 7) * 8;
#pragma unroll
  for (int pass = 0; pass < 2; pass++) {
#pragma unroll
    for (int mh = 0; mh < 2; mh++) {
      const int mt = pass * 2 + mh;
#pragma unroll
      for (int nt = 0; nt < 4; nt++) {
        const float bv = bias[n0 + nw + nt * 16 + l16];
#pragma unroll
        for (int i = 0; i < 4; i++)
          eps[(mh * 16 + quad * 4 + i) * 68 + nt * 16 + l16] =
              acc[mt][nt][i] + bv;
      }
    }
    asm volatile("s_waitcnt lgkmcnt(0)" ::: "memory");
#pragma unroll
    for (int j = 0; j < 4; j++) {
      const int r = j * 8 + erow;
      const int m = m0 + mw + pass * 32 + r;
      const int n = n0 + nw + ec;
      f32x4 v0 = *(const f32x4*)&eps[r * 68 + ec];
      f32x4 v1 = *(const f32x4*)&eps[r * 68 + ec + 4];
      float v[8] = {v0[0], v0[1], v0[2], v0[3], v1[0], v1[1], v1[2], v1[3]};
      if (res) {
        ushort8 rv = *(const ushort8*)((const unsigned short*)res +
                                       (size_t)m * N + n);
#pragma unroll
        for (int t = 0; t < 8; t++) v[t] += b2f(rv[t]);
      }
      ushort8 o;
#pragma unroll
      for (int t = 0; t < 8; t++) {
        float x = (act == 1) ? fmaxf(v[t], 0.0f) : v[t];
        o[t] = f2b(x);
      }
      *(ushort8*)((unsigned short*)C + (size_t)m * N + n) = o;
    }
    asm volatile("s_waitcnt lgkmcnt(0)" ::: "memory");
  }
}

// ---------------------------------------------------------------------------
// fp32 SIMT GEMM (kept for the tiny head): 64x64 tile.
__global__ __launch_bounds__(256) void gemm_k(
    const float* __restrict__ A, const float* __restrict__ W,
    const float* __restrict__ bias, const float* __restrict__ res,
    float* __restrict__ C, int M, int N, int K, int act) {
  __shared__ float As[16][68];
  __shared__ float Ws[16][68];
  const int tid = threadIdx.x;
  const int tx = tid & 15, ty = tid >> 4;
  const int m0 = blockIdx.y * 64, n0 = blockIdx.x * 64;
  const int lr = tid >> 2;
  const int lk = (tid & 3) * 4;
  float acc[4][4] = {{0.f}};
  for (int k0 = 0; k0 < K; k0 += 16) {
#pragma unroll
    for (int i = 0; i < 4; i++) {
      int k = k0 + lk + i;
      As[lk + i][lr] = (k < K) ? A[(size_t)(m0 + lr) * K + k] : 0.0f;
      Ws[lk + i][lr] = (k < K) ? W[(size_t)(n0 + lr) * K + k] : 0.0f;
    }
    __syncthreads();
#pragma unroll
    for (int kk = 0; kk < 16; kk++) {
      float4 a4 = *(const float4*)&As[kk][ty * 4];
      float4 w4 = *(const float4*)&Ws[kk][tx * 4];
      float a[4] = {a4.x, a4.y, a4.z, a4.w};
      float w[4] = {w4.x, w4.y, w4.z, w4.w};
#pragma unroll
      for (int i = 0; i < 4; i++)
#pragma unroll
        for (int j = 0; j < 4; j++) acc[i][j] += a[i] * w[j];
    }
    __syncthreads();
  }
#pragma unroll
  for (int i = 0; i < 4; i++) {
    int m = m0 + ty * 4 + i;
#pragma unroll
    for (int j = 0; j < 4; j++) {
      int n = n0 + tx * 4 + j;
      float v = acc[i][j] + bias[n];
      if (res) v += res[(size_t)m * N + n];
      if (act == 1) v = fmaxf(v, 0.0f);
      else if (act == 2) v = v / (1.0f + __expf(-v));
      C[(size_t)m * N + n] = v;
    }
  }
}

// ---------------------------------------------------------------------------
// Row LayerNorm over D=512, bf16 in/out, fp32 params. 4 rows/block.
__global__ __launch_bounds__(256) void lnb_k(
    const __hip_bfloat16* __restrict__ in, const float* __restrict__ g,
    const float* __restrict__ b, __hip_bfloat16* __restrict__ out) {
  int row = blockIdx.x * 4 + (threadIdx.x >> 6);
  int lane = threadIdx.x & 63;
  const unsigned short* rp =
      (const unsigned short*)in + (size_t)row * DMODEL + lane * 8;
  ushort8 sv = *(const ushort8*)rp;
  float v[8];
  float s = 0.f;
#pragma unroll
  for (int i = 0; i < 8; i++) { v[i] = b2f(sv[i]); s += v[i]; }
#pragma unroll
  for (int off = 32; off; off >>= 1) s += __shfl_xor(s, off);
  float mu = s * (1.0f / DMODEL);
  float vs = 0.f;
#pragma unroll
  for (int i = 0; i < 8; i++) { float d = v[i] - mu; vs += d * d; }
#pragma unroll
  for (int off = 32; off; off >>= 1) vs += __shfl_xor(vs, off);
  float rs = rsqrtf(vs * (1.0f / DMODEL) + 1e-5f);
  ushort8 o;
#pragma unroll
  for (int i = 0; i < 8; i++) {
    int c = lane * 8 + i;
    o[i] = f2b((v[i] - mu) * rs * g[c] + b[c]);
  }
  *(ushort8*)((unsigned short*)out + (size_t)row * DMODEL + lane * 8) = o;
}

// ---------------------------------------------------------------------------
// MFMA ragged attention, key-split flash halves (r11 + Q-prefetch).
#define MAXNH 128
__global__ __launch_bounds__(256, 3) void attn5_k(
    const __hip_bfloat16* __restrict__ qkv, const int* __restrict__ starts,
    __hip_bfloat16* __restrict__ O1, __hip_bfloat16* __restrict__ O2,
    float* __restrict__ ml) {
  const int half = blockIdx.x & 1;
  const int gh = blockIdx.x >> 1;
  const int g = gh >> 3, h = gh & 7;
  int s0 = starts[g], s1 = starts[g + 1];
  s0 = min(max(s0, 0), N_NODES);
  s1 = min(max(s1, s0), N_NODES);
  const int n = s1 - s0, start = s0;
  if (n == 0) return;
  const int tid = threadIdx.x, wave = tid >> 6, lane = tid & 63;
  const int quad = lane >> 4, l16 = lane & 15;
  unsigned short* Oh = (unsigned short*)(half ? O2 : O1);

  __shared__ __align__(16) unsigned short Ks[128][72];     // K rows [key][d]
  __shared__ __align__(16) unsigned short Vt[64][136];     // V^T [d][key]
  __shared__ __align__(16) unsigned short Ps[4][16][136];  // per-wave P[q][key]

  if (n <= 2 * MAXNH) {
    const int nh1 = (n + 1) >> 1;
    const int k0g = half * nh1;
    const int nh = half ? (n - nh1) : nh1;
    const int ktq = (n + 15) >> 4;

    if (nh == 0) {
      for (int mt = wave; mt < ktq; mt += 4) {
        const int q = mt * 16 + l16;
        if (q < n) {
          short4v z = {0, 0, 0, 0};
#pragma unroll
          for (int dt = 0; dt < 4; dt++)
            *(short4v*)(Oh + (size_t)(start + q) * DMODEL + h * HDIM +
                        dt * 16 + quad * 4) = z;
          if (quad == 0) {
            float2 mlv = {-FLT_MAX, 0.0f};
            *(float2*)(ml + ((size_t)(start + q) * NHEAD + h) * 4 + half * 2) = mlv;
          }
        }
      }
      return;
    }

    // ---- stage K rows of this half ----
    for (int idx = tid; idx < nh * 8; idx += 256) {
      int r = idx >> 3, c = (idx & 7) * 8;
      *(ushort8*)&Ks[r][c] = *(const ushort8*)((const unsigned short*)qkv +
                                               (size_t)(start + k0g + r) * 1536 +
                                               512 + h * HDIM + c);
    }
    for (int idx = tid; idx < 16 * 8; idx += 256) {
      int r = nh + (idx >> 3), c = (idx & 7) * 8;
      if (r < 128) {
        ushort8 z = {0, 0, 0, 0, 0, 0, 0, 0};
        *(ushort8*)&Ks[r][c] = z;
      }
    }
    // ---- stage V transposed ----
    const int vr = tid & 31, dc8 = tid >> 5;
    for (int r0 = 0; r0 < nh; r0 += 32) {
      int r = r0 + vr;
      if (r < nh) {
        ushort8 v = *(const ushort8*)((const unsigned short*)qkv +
                                      (size_t)(start + k0g + r) * 1536 + 1024 +
                                      h * HDIM + dc8 * 8);
#pragma unroll
        for (int j = 0; j < 8; j++) Vt[dc8 * 8 + j][r] = v[j];
      }
    }
    for (int idx = tid; idx < 64 * 32; idx += 256) {
      int d = idx >> 5, r = nh + (idx & 31);
      if (r < 136) Vt[d][r] = 0;
    }
    __syncthreads();

    const int ktmax2 = (nh + 15) >> 4;
    const int nkc2 = (nh + 31) >> 5;
    const float scale = 0.125f;

    // Q prefetch for first iteration
    short8 qf0, qf1;
    if (wave < ktq) {
      const int qrow = start + min(wave * 16 + l16, n - 1);
      qf0 = *(const short8*)((const unsigned short*)qkv + (size_t)qrow * 1536 +
                             h * HDIM + quad * 8);
      qf1 = *(const short8*)((const unsigned short*)qkv + (size_t)qrow * 1536 +
                             h * HDIM + 32 + quad * 8);
    }

    for (int mt = wave; mt < ktq; mt += 4) {
      const short8 cq0 = qf0, cq1 = qf1;
      // prefetch next iteration's Q while current tile computes
      if (mt + 4 < ktq) {
        const int qrow = start + min((mt + 4) * 16 + l16, n - 1);
        qf0 = *(const short8*)((const unsigned short*)qkv +
                               (size_t)qrow * 1536 + h * HDIM + quad * 8);
        qf1 = *(const short8*)((const unsigned short*)qkv +
                               (size_t)qrow * 1536 + h * HDIM + 32 + quad * 8);
      }
      f32x4 sacc[8];
#pragma unroll
      for (int kt = 0; kt < 8; kt++) {
        if (kt < ktmax2) {
          const int krow = kt * 16 + l16;
          const short8 kf0 = *(const short8*)&Ks[krow][quad * 8];
          const short8 kf1 = *(const short8*)&Ks[krow][32 + quad * 8];
          f32x4 a = {0.f, 0.f, 0.f, 0.f};
          a = __builtin_amdgcn_mfma_f32_16x16x32_bf16(kf0, cq0, a, 0, 0, 0);
          a = __builtin_amdgcn_mfma_f32_16x16x32_bf16(kf1, cq1, a, 0, 0, 0);
          sacc[kt] = a;
        }
      }
      float mx = -FLT_MAX;
#pragma unroll
      for (int kt = 0; kt < 8; kt++) {
        if (kt < ktmax2) {
#pragma unroll
          for (int i = 0; i < 4; i++) {
            const int key = kt * 16 + quad * 4 + i;
            const float v = sacc[kt][i] * scale;
            sacc[kt][i] = v;
            if (key < nh) mx = fmaxf(mx, v);
          }
        }
      }
      mx = fmaxf(mx, __shfl_xor(mx, 16));
      mx = fmaxf(mx, __shfl_xor(mx, 32));
      float ls = 0.f;
#pragma unroll
      for (int kt = 0; kt < 8; kt++) {
        if (kt < ktmax2) {
#pragma unroll
          for (int i = 0; i < 4; i++) {
            const int key = kt * 16 + quad * 4 + i;
            const float p = (key < nh) ? __expf(sacc[kt][i] - mx) : 0.0f;
            sacc[kt][i] = p;
            ls += p;
          }
        }
      }
      ls += __shfl_xor(ls, 16);
      ls += __shfl_xor(ls, 32);
#pragma unroll
      for (int kt = 0; kt < 8; kt++) {
        if (kt < 2 * nkc2) {
          short4v pp;
#pragma unroll
          for (int i = 0; i < 4; i++) {
            const float p = (kt < ktmax2) ? sacc[kt][i] : 0.0f;
            pp[i] = (short)f2b(p);
          }
          *(short4v*)&Ps[wave][l16][kt * 16 + quad * 4] = pp;
        }
      }
      asm volatile("s_waitcnt lgkmcnt(0)" ::: "memory");
      const int qv = mt * 16 + l16;
#pragma unroll
      for (int dt = 0; dt < 4; dt++) {
        f32x4 oa = {0.f, 0.f, 0.f, 0.f};
#pragma unroll
        for (int kc = 0; kc < 4; kc++) {
          if (kc < nkc2) {
            const short8 vf = *(const short8*)&Vt[dt * 16 + l16][kc * 32 + quad * 8];
            const short8 pf = *(const short8*)&Ps[wave][l16][kc * 32 + quad * 8];
            oa = __builtin_amdgcn_mfma_f32_16x16x32_bf16(vf, pf, oa, 0, 0, 0);
          }
        }
        if (qv < n) {
          short4v ov;
#pragma unroll
          for (int i = 0; i < 4; i++) ov[i] = (short)f2b(oa[i]);
          *(short4v*)(Oh + (size_t)(start + qv) * DMODEL + h * HDIM +
                      dt * 16 + quad * 4) = ov;
        }
      }
      if (qv < n && quad == 0) {
        float2 mlv = {mx, ls};
        *(float2*)(ml + ((size_t)(start + qv) * NHEAD + h) * 4 + half * 2) = mlv;
      }
    }
  } else {
    // fallback (n in (256,512]; statistically never).
    const float scale = 0.125f;
    int nn = min(n, 512);
    if (half == 1) {
      for (int qi = wave; qi < nn; qi += 4) {
        Oh[(size_t)(start + qi) * DMODEL + h * HDIM + lane] = 0;
        if (lane == 0) {
          float2 mlv = {-FLT_MAX, 0.0f};
          *(float2*)(ml + ((size_t)(start + qi) * NHEAD + h) * 4 + 2) = mlv;
        }
      }
      return;
    }
    for (int qi = wave; qi < nn; qi += 4) {
      float qd = __bfloat162float(
          qkv[(size_t)(start + qi) * (3 * DMODEL) + h * HDIM + lane]);
      float sreg[8];
#pragma unroll
      for (int t = 0; t < 8; t++) {
        float sc = -FLT_MAX;
        if (t * 64 < nn) {
          int k = t * 64 + lane, kc = min(k, nn - 1);
          const __hip_bfloat16* Kr =
              qkv + (size_t)(start + kc) * (3 * DMODEL) + DMODEL + h * HDIM;
          float a = 0.f;
#pragma unroll
          for (int d = 0; d < 64; d++)
            a += __shfl(qd, d) * __bfloat162float(Kr[d]);
          if (k < nn) sc = a * scale;
        }
        sreg[t] = sc;
      }
      float m = -FLT_MAX;
#pragma unroll
      for (int t = 0; t < 8; t++) m = fmaxf(m, sreg[t]);
#pragma unroll
      for (int off = 32; off; off >>= 1) m = fmaxf(m, __shfl_xor(m, off));
      float lsum = 0.f;
#pragma unroll
      for (int t = 0; t < 8; t++) {
        float p = (sreg[t] == -FLT_MAX) ? 0.0f : __expf(sreg[t] - m);
        sreg[t] = p;
        lsum += p;
      }
#pragma unroll
      for (int off = 32; off; off >>= 1) lsum += __shfl_xor(lsum, off);
      float inv_l = 1.0f / lsum;
      float o = 0.f;
#pragma unroll
      for (int t = 0; t < 8; t++) {
        int kb = t * 64;
        if (kb < nn) {
          int kmax = min(64, nn - kb);
          const __hip_bfloat16* Vb = qkv + (size_t)(start + kb) * (3 * DMODEL) +
                                     2 * DMODEL + h * HDIM + lane;
          for (int j = 0; j < kmax; j++)
            o += __shfl(sreg[t], j) *
                 __bfloat162float(Vb[(size_t)j * (3 * DMODEL)]);
        }
      }
      Oh[(size_t)(start + qi) * DMODEL + h * HDIM + lane] = f2b(o * inv_l);
      if (lane == 0) {
        float2 mlv = {0.0f, 1.0f};
        *(float2*)(ml + ((size_t)(start + qi) * NHEAD + h) * 4) = mlv;
      }
    }
  }
}

// ---------------------------------------------------------------------------
// Merge the two key-half partials.
__global__ __launch_bounds__(256) void merge_k(
    const __hip_bfloat16* __restrict__ O1, const __hip_bfloat16* __restrict__ O2,
    const float* __restrict__ ml, __hip_bfloat16* __restrict__ out) {
  int t = blockIdx.x * 256 + threadIdx.x;
  int node = t >> 6;
  int rem = t & 63;
  int h = rem >> 3;
  int c8 = (rem & 7) * 8;
  float4 m4 = *(const float4*)(ml + ((size_t)node * NHEAD + h) * 4);
  float mm = fmaxf(m4.x, m4.z);
  float w1 = __expf(m4.x - mm), w2 = __expf(m4.z - mm);
  float inv = 1.0f / (w1 * m4.y + w2 * m4.w);
  size_t off = (size_t)node * DMODEL + h * HDIM + c8;
  ushort8 a = *(const ushort8*)((const unsigned short*)O1 + off);
  ushort8 b = *(const ushort8*)((const unsigned short*)O2 + off);
  ushort8 o;
#pragma unroll
  for (int i = 0; i < 8; i++)
    o[i] = f2b((w1 * b2f(a[i]) + w2 * b2f(b[i])) * inv);
  *(ushort8*)((unsigned short*)out + off) = o;
}

// ---------------------------------------------------------------------------
__global__ __launch_bounds__(256) void pool_k(
    const __hip_bfloat16* __restrict__ hp, const int* __restrict__ starts,
    float* __restrict__ pooled) {
  int g = blockIdx.x;
  int s0 = starts[g], s1 = starts[g + 1];
  s0 = min(max(s0, 0), N_NODES);
  s1 = min(max(s1, s0), N_NODES);
  int n = s1 - s0;
  float inv = n > 0 ? 1.0f / (float)n : 0.0f;
  int c = blockIdx.y * 256 + threadIdx.x;
  float acc = 0.f;
  for (int r = s0; r < s1; r++)
    acc += __bfloat162float(hp[(size_t)r * DMODEL + c]);
  pooled[(size_t)g * DMODEL + c] = acc * inv;
}

// ---------------------------------------------------------------------------
__global__ __launch_bounds__(256) void head2_k(
    const float* __restrict__ h1, const float* __restrict__ w2,
    const float* __restrict__ b2, float* __restrict__ y) {
  int row = blockIdx.x * 4 + (threadIdx.x >> 6);
  int lane = threadIdx.x & 63;
  float s = 0.f;
#pragma unroll
  for (int i = 0; i < 8; i++) {
    int c = lane + i * 64;
    s += h1[(size_t)row * DMODEL + c] * w2[c];
  }
#pragma unroll
  for (int off = 32; off; off >>= 1) s += __shfl_xor(s, off);
  if (lane == 0) y[row] = s + b2[0];
}

// ---------------------------------------------------------------------------
extern "C" void kernel_launch(void* const* d_in, const int* in_sizes, int n_in,
                              void* d_out, int out_size, void* d_ws,
                              size_t ws_size, hipStream_t stream) {
  const float* node_features = (const float*)d_in[0];
  const int* batch = (const int*)d_in[3];
  const float* emb_w = (const float*)d_in[4];
  const float* emb_b = (const float*)d_in[5];
  const float* in_proj_w = (const float*)d_in[6];
  const float* in_proj_b = (const float*)d_in[7];
  const float* out_w = (const float*)d_in[8];
  const float* out_b = (const float*)d_in[9];
  const float* ln1_g = (const float*)d_in[10];
  const float* ln1_b = (const float*)d_in[11];
  const float* ffn_w1 = (const float*)d_in[12];
  const float* ffn_b1 = (const float*)d_in[13];
  const float* ffn_w2 = (const float*)d_in[14];
  const float* ffn_b2 = (const float*)d_in[15];
  const float* ln2_g = (const float*)d_in[16];
  const float* ln2_b = (const float*)d_in[17];
  const float* head_w1 = (const float*)d_in[18];
  const float* head_b1 = (const float*)d_in[19];
  const float* head_w2 = (const float*)d_in[20];
  const float* head_b2 = (const float*)d_in[21];
  float* y = (float*)d_out;

  typedef __hip_bfloat16 bf;
  char* wsb = (char*)d_ws;
  int* starts = (int*)wsb;
  bf* nf_b = (bf*)(wsb + 1024);                        // N x 96
  bf* wq_b = nf_b + (size_t)N_NODES * D_INP;           // L x 1536 x 512
  bf* wo_b = wq_b + (size_t)NLAYER * 3 * DMODEL * DMODEL;
  bf* w1_b = wo_b + (size_t)NLAYER * DMODEL * DMODEL;
  bf* w2_b = w1_b + (size_t)NLAYER * DFF * DMODEL;
  bf* we_b = w2_b + (size_t)NLAYER * DMODEL * DFF;     // 512 x 96
  bf* hp   = we_b + (size_t)DMODEL * D_INP;            // N x 512
  bf* xb   = hp + (size_t)N_NODES * DMODEL;            // N x 512 (O2 half)
  bf* t1b  = xb + (size_t)N_NODES * DMODEL;            // N x 512 (O1 half / attn out)
  bf* qkvb = t1b + (size_t)N_NODES * DMODEL;           // N x 1536
  bf* ffh  = qkvb;                                     // N x 2048 (overlays qkv)
  float* pooled = (float*)((char*)ffh + (size_t)N_NODES * DFF * 2);
  float* h1 = pooled + (size_t)B_GRAPHS * DMODEL;
  float* ml = h1 + (size_t)B_GRAPHS * DMODEL;          // N x 8 x 4 floats

  starts_k<<<1, 256, 0, stream>>>(batch, starts);

  // one-dispatch conversion of all weights + padded nf/emb_w
  prep_k<<<(QTOT + 255) / 256, 256, 0, stream>>>(
      in_proj_w, out_w, ffn_w1, ffn_w2, node_features, emb_w,
      wq_b, wo_b, w1_b, w2_b, nf_b, we_b);

  // embed: hp = nf @ emb_w^T + emb_b  (K=96)
  mgemm_k<<<(N_NODES / 128) * (DMODEL / 128), 256, 0, stream>>>(
      nf_b, we_b, emb_b, nullptr, hp, N_NODES, DMODEL, D_INP, 0);

  for (int l = 0; l < NLAYER; l++) {
    const bf* wq = wq_b + (size_t)l * 3 * DMODEL * DMODEL;
    const bf* wo = wo_b + (size_t)l * DMODEL * DMODEL;
    const bf* w1 = w1_b + (size_t)l * DFF * DMODEL;
    const bf* w2 = w2_b + (size_t)l * DMODEL * DFF;
    const float* ipb = in_proj_b + (size_t)l * 3 * DMODEL;
    const float* ob = out_b + (size_t)l * DMODEL;
    const float* b1 = ffn_b1 + (size_t)l * DFF;
    const float* b2 = ffn_b2 + (size_t)l * DMODEL;

    // qkv = hp @ in_proj^T + b
    mgemm_k<<<(N_NODES / 128) * (3 * DMODEL / 128), 256, 0, stream>>>(
        hp, wq, ipb, nullptr, qkvb, N_NODES, 3 * DMODEL, DMODEL, 0);

    // attention halves -> t1b (half0) / xb (half1), then merge -> t1b
    attn5_k<<<B_GRAPHS * NHEAD * 2, 256, 0, stream>>>(qkvb, starts, t1b, xb, ml);
    merge_k<<<N_NODES * 64 / 256, 256, 0, stream>>>(t1b, xb, ml, t1b);

    // xb = t1b @ out_w^T + out_b + hp ; then LN in-place
    mgemm_k<<<(N_NODES / 128) * (DMODEL / 128), 256, 0, stream>>>(
        t1b, wo, ob, hp, xb, N_NODES, DMODEL, DMODEL, 0);
    lnb_k<<<N_NODES / 4, 256, 0, stream>>>(xb, ln1_g + l * DMODEL,
                                           ln1_b + l * DMODEL, xb);

    // FFN, single dispatch each (ffh overlays the dead qkv region)
    mgemm_k<<<(N_NODES / 128) * (DFF / 128), 256, 0, stream>>>(
        xb, w1, b1, nullptr, ffh, N_NODES, DFF, DMODEL, 1);
    mgemm_k<<<(N_NODES / 128) * (DMODEL / 128), 256, 0, stream>>>(
        ffh, w2, b2, xb, t1b, N_NODES, DMODEL, DFF, 0);

    lnb_k<<<N_NODES / 4, 256, 0, stream>>>(t1b, ln2_g + l * DMODEL,
                                           ln2_b + l * DMODEL, hp);
  }

  pool_k<<<dim3(B_GRAPHS, 2), 256, 0, stream>>>(hp, starts, pooled);
  gemm_k<<<dim3(DMODEL / 64, B_GRAPHS / 64), 256, 0, stream>>>(
      pooled, head_w1, head_b1, nullptr, h1, B_GRAPHS, DMODEL, DMODEL, 2);
  head2_k<<<B_GRAPHS / 4, 256, 0, stream>>>(h1, head_w2, head_b2, y);
}